// Round 4
// baseline (2648.744 us; speedup 1.0000x reference)
//
#include <hip/hip_runtime.h>
#include <hip/hip_bf16.h>

#define B_ 4
#define N_ 2048
#define E_ 512
#define EMB_ 1024
#define H_ 8
#define D_ 128
#define KNN_ 16

// ---------------------------------------------------------------------------
// K0: sq[b,e] = np.sum(xt*xt, -1) emulating numpy's pairwise_sum on the
// contiguous fp32 temp: 2048 -> binary tree over 16 blocks of 128; each
// 128-block: 8 SIMD regs of 16 lanes r_j = prod[j*16+l], combined
// ((r0+r1)+(r2+r3))+((r4+r5)+(r6+r7)); then lane halving tree
// b_l=a_l+a_{l+8}; c_l=b_l+b_{l+4}; (c0+c1)+(c2+c3)  (gcc _mm512_reduce_add).
// All __fmul_rn/__fadd_rn to forbid FMA/reassociation.
// ---------------------------------------------------------------------------
__global__ __launch_bounds__(256) void k_sqnp(const float* __restrict__ x,
                                              float* __restrict__ sq) {
  const int t = blockIdx.x * 256 + threadIdx.x;   // b*E + e
  if (t >= B_ * E_) return;
  const int b = t >> 9, e = t & (E_ - 1);
  const float* xb = x + (size_t)b * N_ * E_ + e;
  float bs[16];
  for (int blk = 0; blk < 16; blk++) {
    const float* p = xb + (size_t)blk * 128 * E_;
    float lane[16];
#pragma unroll
    for (int l = 0; l < 16; l++) {
      float pr[8];
#pragma unroll
      for (int j = 0; j < 8; j++) {
        float v = p[(size_t)(j * 16 + l) * E_];
        pr[j] = __fmul_rn(v, v);
      }
      float s01 = __fadd_rn(pr[0], pr[1]);
      float s23 = __fadd_rn(pr[2], pr[3]);
      float s45 = __fadd_rn(pr[4], pr[5]);
      float s67 = __fadd_rn(pr[6], pr[7]);
      lane[l] = __fadd_rn(__fadd_rn(s01, s23), __fadd_rn(s45, s67));
    }
    float bb[8];
#pragma unroll
    for (int l = 0; l < 8; l++) bb[l] = __fadd_rn(lane[l], lane[l + 8]);
    float cc[4];
#pragma unroll
    for (int l = 0; l < 4; l++) cc[l] = __fadd_rn(bb[l], bb[l + 4]);
    bs[blk] = __fadd_rn(__fadd_rn(cc[0], cc[1]), __fadd_rn(cc[2], cc[3]));
  }
  float t1[8], t2[4];
#pragma unroll
  for (int l = 0; l < 8; l++) t1[l] = __fadd_rn(bs[2 * l], bs[2 * l + 1]);
#pragma unroll
  for (int l = 0; l < 4; l++) t2[l] = __fadd_rn(t1[2 * l], t1[2 * l + 1]);
  sq[t] = __fadd_rn(__fadd_rn(t2[0], t2[1]), __fadd_rn(t2[2], t2[3]));
}

// ---------------------------------------------------------------------------
// K1: g[b,i,j] = einsum('ben,bfn->bef') emulating numpy's scalar sequential
// sum-of-products (strided operands -> non-SIMD, no-FMA loop): a single fp32
// chain accum = fadd(accum, fmul(xi[n], xj[n])), n = 0..2047 ascending.
// 32x32 tile per block, 2x2 outputs per thread, LDS-staged 32-n chunks.
// ---------------------------------------------------------------------------
__global__ __launch_bounds__(256) void k_gramnp(const float* __restrict__ x,
                                                float* __restrict__ g) {
  __shared__ float xi[32][36];
  __shared__ float xj[32][36];
  const int tid = threadIdx.x;
  const int i0 = blockIdx.x * 32, j0 = blockIdx.y * 32, b = blockIdx.z;
  const int il = tid & 15, jl = tid >> 4;
  const float* xb = x + (size_t)b * N_ * E_;
  float a00 = 0.f, a01 = 0.f, a10 = 0.f, a11 = 0.f;
  const int sc = tid & 31;        // channel within tile
  const int sr0 = tid >> 5;       // 0..7
  for (int n0 = 0; n0 < N_; n0 += 32) {
    __syncthreads();
#pragma unroll
    for (int rr = 0; rr < 4; rr++) {
      const int nn = sr0 + rr * 8;
      xi[sc][nn] = xb[(size_t)(n0 + nn) * E_ + i0 + sc];
      xj[sc][nn] = xb[(size_t)(n0 + nn) * E_ + j0 + sc];
    }
    __syncthreads();
#pragma unroll
    for (int nn = 0; nn < 32; nn++) {
      const float va0 = xi[il][nn],      va1 = xi[il + 16][nn];
      const float vb0 = xj[jl][nn],      vb1 = xj[jl + 16][nn];
      a00 = __fadd_rn(a00, __fmul_rn(va0, vb0));
      a01 = __fadd_rn(a01, __fmul_rn(va0, vb1));
      a10 = __fadd_rn(a10, __fmul_rn(va1, vb0));
      a11 = __fadd_rn(a11, __fmul_rn(va1, vb1));
    }
  }
  float* gb = g + ((size_t)b * E_ + i0) * E_ + j0;
  gb[(size_t)il * E_ + jl]             = a00;
  gb[(size_t)il * E_ + jl + 16]        = a01;
  gb[(size_t)(il + 16) * E_ + jl]      = a10;
  gb[(size_t)(il + 16) * E_ + jl + 16] = a11;
}

// ---------------------------------------------------------------------------
// K2: top-16 smallest dist per (b,i): dist = fl(fl(sq_i+sq_j) - fl(2*g)),
// all fp32 ops (no FMA). Iterative argmin, ties -> lower index (stable).
// ---------------------------------------------------------------------------
__global__ __launch_bounds__(256) void k_topk(const float* __restrict__ sq,
                                              const float* __restrict__ g,
                                              int* __restrict__ idxout) {
  const int bi = blockIdx.x;            // b*E + i
  const int b = bi >> 9, i = bi & (E_ - 1);
  const int tid = threadIdx.x;
  const float* gb = g + ((size_t)b * E_ + i) * E_;
  const float* sqb = sq + ((size_t)b << 9);
  __shared__ float val[E_];
  __shared__ float rv[256];
  __shared__ int ri[256];
  const float sqi = sqb[i];
  for (int j = tid; j < E_; j += 256) {
    val[j] = __fsub_rn(__fadd_rn(sqi, sqb[j]), __fmul_rn(2.0f, gb[j]));
  }
  __syncthreads();
  for (int t = 0; t < KNN_; t++) {
    float best = 3.0e38f; int bidx = E_;
    for (int j = tid; j < E_; j += 256) {
      float v = val[j];
      if (v < best) { best = v; bidx = j; }   // strict < keeps lower index
    }
    rv[tid] = best; ri[tid] = bidx;
    __syncthreads();
    for (int s = 128; s > 0; s >>= 1) {
      if (tid < s) {
        float v2 = rv[tid + s]; int i2 = ri[tid + s];
        if (v2 < rv[tid] || (v2 == rv[tid] && i2 < ri[tid])) {
          rv[tid] = v2; ri[tid] = i2;
        }
      }
      __syncthreads();
    }
    if (tid == 0) {
      idxout[(size_t)bi * KNN_ + t] = ri[0];
      val[ri[0]] = 3.0e38f;
    }
    __syncthreads();
  }
}

// ---------------------------------------------------------------------------
// K3: x_knn mean + interleaved q into output's q half. np.mean over axis=2
// (non-inner axis) is SEQUENTIAL over k -> plain ordered sum then /16.
// out[b,n,2i] = x[b,n,i]; out[b,n,2i+1] = mean.
// ---------------------------------------------------------------------------
__global__ __launch_bounds__(256) void k_knnmean(const float* __restrict__ x,
                                                 const int* __restrict__ idx,
                                                 float* __restrict__ out) {
  const int n = blockIdx.x, b = blockIdx.y;
  const int tid = threadIdx.x;
  __shared__ float xrow[E_];
  const float* xr = x + ((size_t)b * N_ + n) * E_;
  for (int i = tid; i < E_; i += 256) xrow[i] = xr[i];
  __syncthreads();
  float* orow = out + ((size_t)b * (2 * N_) + n) * EMB_;
  for (int i = tid; i < E_; i += 256) {
    const int* id = idx + ((size_t)b * E_ + i) * KNN_;
    float s = 0.f;
#pragma unroll
    for (int t = 0; t < KNN_; t++) s = __fadd_rn(s, xrow[id[t]]);
    float2 w; w.x = xrow[i]; w.y = s * (1.0f / 16.0f);
    *(float2*)&orow[2 * i] = w;
  }
}

// ---------------------------------------------------------------------------
// K4: generic projection GEMM  Y[m,o] = sum_e X[m,e] * W[o,e] + bias[o]
// M = B*N = 8192, K = Nout = 1024. Row m -> (b = m/N, n = m%N);
// X row at X + b*xbs + n*EMB ; Y row at Y + b*ybs + yoff + n*EMB.
// 128x128 tile, 256 threads, 8x8 per thread, k-chunk 16.
// ---------------------------------------------------------------------------
__global__ __launch_bounds__(256) void k_gemm(const float* __restrict__ X, int xbs,
                                              const float* __restrict__ W,
                                              const float* __restrict__ bias,
                                              float* __restrict__ Y, int ybs, int yoff) {
  __shared__ float As[16][132];
  __shared__ float Bs[16][132];
  const int tid = threadIdx.x;
  const int tx = tid & 15, ty = tid >> 4;
  const int row0 = blockIdx.x * 128, col0 = blockIdx.y * 128;
  float acc[8][8];
#pragma unroll
  for (int i = 0; i < 8; i++)
#pragma unroll
    for (int j = 0; j < 8; j++) acc[i][j] = 0.f;

  const int r = tid >> 1;           // 0..127
  const int kk = (tid & 1) * 8;     // 0 or 8
  const int m = row0 + r, bb = m >> 11, nn = m & (N_ - 1);
  const float* xrow = X + (size_t)bb * xbs + (size_t)nn * EMB_;
  const float* wrow = W + (size_t)(col0 + r) * EMB_;

  for (int k0 = 0; k0 < EMB_; k0 += 16) {
    float4 a0 = *(const float4*)(xrow + k0 + kk);
    float4 a1 = *(const float4*)(xrow + k0 + kk + 4);
    float4 w0 = *(const float4*)(wrow + k0 + kk);
    float4 w1 = *(const float4*)(wrow + k0 + kk + 4);
    __syncthreads();
    As[kk + 0][r] = a0.x; As[kk + 1][r] = a0.y; As[kk + 2][r] = a0.z; As[kk + 3][r] = a0.w;
    As[kk + 4][r] = a1.x; As[kk + 5][r] = a1.y; As[kk + 6][r] = a1.z; As[kk + 7][r] = a1.w;
    Bs[kk + 0][r] = w0.x; Bs[kk + 1][r] = w0.y; Bs[kk + 2][r] = w0.z; Bs[kk + 3][r] = w0.w;
    Bs[kk + 4][r] = w1.x; Bs[kk + 5][r] = w1.y; Bs[kk + 6][r] = w1.z; Bs[kk + 7][r] = w1.w;
    __syncthreads();
#pragma unroll
    for (int k = 0; k < 16; k++) {
      float av[8], bv[8];
      *(float4*)&av[0] = *(const float4*)&As[k][ty * 8];
      *(float4*)&av[4] = *(const float4*)&As[k][ty * 8 + 4];
      *(float4*)&bv[0] = *(const float4*)&Bs[k][tx * 8];
      *(float4*)&bv[4] = *(const float4*)&Bs[k][tx * 8 + 4];
#pragma unroll
      for (int i = 0; i < 8; i++)
#pragma unroll
        for (int j = 0; j < 8; j++) acc[i][j] += av[i] * bv[j];
    }
  }
#pragma unroll
  for (int i = 0; i < 8; i++) {
    const int mm = row0 + ty * 8 + i;
    const int bb2 = mm >> 11, nn2 = mm & (N_ - 1);
    float* yrow = Y + (size_t)bb2 * ybs + yoff + (size_t)nn2 * EMB_ + col0 + tx * 8;
#pragma unroll
    for (int j4 = 0; j4 < 8; j4 += 4) {
      float4 o;
      o.x = acc[i][j4 + 0] + bias[col0 + tx * 8 + j4 + 0];
      o.y = acc[i][j4 + 1] + bias[col0 + tx * 8 + j4 + 1];
      o.z = acc[i][j4 + 2] + bias[col0 + tx * 8 + j4 + 2];
      o.w = acc[i][j4 + 3] + bias[col0 + tx * 8 + j4 + 3];
      *(float4*)&yrow[j4] = o;
    }
  }
}

// ---------------------------------------------------------------------------
// K5: flash-style fp32 attention per (b,h). 64-row Q tile per block,
// 32-key tiles, K/V share one LDS buffer (keeps static LDS < 64KB).
// ---------------------------------------------------------------------------
__global__ __launch_bounds__(256) void k_flash(const float* __restrict__ Qg,
                                               const float* __restrict__ Kg,
                                               const float* __restrict__ Vg,
                                               float* __restrict__ Og) {
  __shared__ float Qs[64][132];
  __shared__ float KVs[32][132];
  __shared__ float Ps[64][33];
  __shared__ float mrow[64], lrow[64], alpha_s[64];
  __shared__ float red[4][64];
  const int tid = threadIdx.x;
  const int rt = blockIdx.x, bh = blockIdx.y;
  const int b = bh >> 3, h = bh & 7;
  const float scale = 0.08838834764831845f;  // 1/sqrt(128)
  const size_t headoff = (size_t)h * D_;

  const float* Qbase = Qg + ((size_t)b * N_ + rt * 64) * EMB_ + headoff;
  for (int t = tid; t < 64 * 32; t += 256) {
    int row = t >> 5, c4 = (t & 31) * 4;
    float4 v = *(const float4*)(Qbase + (size_t)row * EMB_ + c4);
    v.x *= scale; v.y *= scale; v.z *= scale; v.w *= scale;
    *(float4*)&Qs[row][c4] = v;
  }
  if (tid < 64) { mrow[tid] = -3.0e38f; lrow[tid] = 0.f; }

  float o[32];
#pragma unroll
  for (int j = 0; j < 32; j++) o[j] = 0.f;

  const int sr = tid >> 2;   // 0..63 : S-phase row
  const int kcg = tid & 3;   // kc = 4*i + kcg  (bank-friendly)
  const int rr = tid & 63;   // PV row
  const int cg = tid >> 6;   // PV col group (0..3) -> cols cg*32..

  for (int kt = 0; kt < N_ / 32; kt++) {
    __syncthreads();                     // prev PV done with KVs / red
    const float* Kbase = Kg + ((size_t)b * N_ + kt * 32) * EMB_ + headoff;
    for (int t = tid; t < 32 * 32; t += 256) {
      int row = t >> 5, c4 = (t & 31) * 4;
      *(float4*)&KVs[row][c4] = *(const float4*)(Kbase + (size_t)row * EMB_ + c4);
    }
    __syncthreads();
    // S[sr][kc] for kc = 4*i+kcg
    float s[8];
#pragma unroll
    for (int i = 0; i < 8; i++) s[i] = 0.f;
    for (int d4 = 0; d4 < D_; d4 += 4) {
      float4 qv = *(const float4*)&Qs[sr][d4];
#pragma unroll
      for (int i = 0; i < 8; i++) {
        float4 kv = *(const float4*)&KVs[4 * i + kcg][d4];
        s[i] += qv.x * kv.x + qv.y * kv.y + qv.z * kv.z + qv.w * kv.w;
      }
    }
    float lm = s[0];
#pragma unroll
    for (int i = 1; i < 8; i++) lm = fmaxf(lm, s[i]);
    red[kcg][sr] = lm;
    __syncthreads();                     // K reads complete after this
    if (tid < 64) {
      float tm = fmaxf(fmaxf(red[0][tid], red[1][tid]),
                       fmaxf(red[2][tid], red[3][tid]));
      float mo = mrow[tid];
      float mn = fmaxf(mo, tm);
      mrow[tid] = mn;
      alpha_s[tid] = __expf(mo - mn);
    }
    // load V into the shared buffer (K no longer needed)
    const float* Vbase = Vg + ((size_t)b * N_ + kt * 32) * EMB_ + headoff;
    for (int t = tid; t < 32 * 32; t += 256) {
      int row = t >> 5, c4 = (t & 31) * 4;
      *(float4*)&KVs[row][c4] = *(const float4*)(Vbase + (size_t)row * EMB_ + c4);
    }
    __syncthreads();
    {
      float mn = mrow[sr];
      float ls = 0.f;
#pragma unroll
      for (int i = 0; i < 8; i++) {
        float p = __expf(s[i] - mn);
        Ps[sr][4 * i + kcg] = p;
        ls += p;
      }
      red[kcg][sr] = ls;
    }
    __syncthreads();
    if (tid < 64) {
      lrow[tid] = lrow[tid] * alpha_s[tid] +
                  red[0][tid] + red[1][tid] + red[2][tid] + red[3][tid];
    }
    // PV: O[rr][cg*32+j] update
    float al = alpha_s[rr];
#pragma unroll
    for (int j = 0; j < 32; j++) o[j] *= al;
    for (int kc = 0; kc < 32; kc++) {
      float p = Ps[rr][kc];
      const float4* vr = (const float4*)&KVs[kc][cg * 32];
#pragma unroll
      for (int j4 = 0; j4 < 8; j4++) {
        float4 vv = vr[j4];
        o[j4 * 4 + 0] += p * vv.x; o[j4 * 4 + 1] += p * vv.y;
        o[j4 * 4 + 2] += p * vv.z; o[j4 * 4 + 3] += p * vv.w;
      }
    }
  }
  __syncthreads();
  float linv = 1.0f / lrow[rr];
  float* orow = Og + ((size_t)b * N_ + rt * 64 + rr) * EMB_ + headoff + cg * 32;
#pragma unroll
  for (int j4 = 0; j4 < 8; j4++) {
    float4 w;
    w.x = o[j4 * 4 + 0] * linv; w.y = o[j4 * 4 + 1] * linv;
    w.z = o[j4 * 4 + 2] * linv; w.w = o[j4 * 4 + 3] * linv;
    *(float4*)&orow[j4 * 4] = w;
  }
}

// ---------------------------------------------------------------------------
extern "C" void kernel_launch(void* const* d_in, const int* in_sizes, int n_in,
                              void* d_out, int out_size, void* d_ws, size_t ws_size,
                              hipStream_t stream) {
  const float* x     = (const float*)d_in[0];
  const float* x_enc = (const float*)d_in[1];
  const float* w_in  = (const float*)d_in[2];
  const float* b_in  = (const float*)d_in[3];
  const float* w_out = (const float*)d_in[4];
  const float* b_out = (const float*)d_in[5];
  float* out = (float*)d_out;
  float* ws  = (float*)d_ws;

  const size_t szG   = (size_t)B_ * E_ * E_;      // 1,048,576 floats (4 MB)
  const size_t szSq  = (size_t)B_ * E_;           // 2048 floats
  const size_t szIdx = (size_t)B_ * E_ * KNN_;    // 32,768 ints
  const size_t szBuf = (size_t)B_ * N_ * EMB_;    // 8,388,608 floats

  float* g   = ws;
  float* sqv = ws + szG;
  int*   idx = (int*)(ws + szG + szSq);
  float* Qb  = ws + szG + szSq + szIdx;
  float* Kb  = Qb + szBuf;
  float* Vb  = Kb + szBuf;
  // O aliases Q if workspace is tight (safe: each flash block's O-write
  // region is exactly the Q region only that block reads, staged to LDS
  // before any O write).
  const size_t needFull = (szG + szSq + szIdx + 4 * szBuf) * sizeof(float);
  float* Ob = (ws_size >= needFull) ? (Vb + szBuf) : Qb;

  // 1) kNN emulating the numpy reference's fp32 numerics exactly
  k_sqnp<<<dim3((B_ * E_ + 255) / 256), 256, 0, stream>>>(x, sqv);
  k_gramnp<<<dim3(E_ / 32, E_ / 32, B_), 256, 0, stream>>>(x, g);
  k_topk<<<dim3(B_ * E_), 256, 0, stream>>>(sqv, g, idx);
  k_knnmean<<<dim3(N_, B_), 256, 0, stream>>>(x, idx, out);

  // 2) projections: Q from q (lives in out, batch stride 2N*EMB), K/V from x_enc
  k_gemm<<<dim3(64, 8), 256, 0, stream>>>(out, 2 * N_ * EMB_, w_in, b_in,
                                          Qb, N_ * EMB_, 0);
  k_gemm<<<dim3(64, 8), 256, 0, stream>>>(x_enc, N_ * EMB_, w_in + (size_t)EMB_ * EMB_,
                                          b_in + EMB_, Kb, N_ * EMB_, 0);
  k_gemm<<<dim3(64, 8), 256, 0, stream>>>(x_enc, N_ * EMB_, w_in + 2 * (size_t)EMB_ * EMB_,
                                          b_in + 2 * EMB_, Vb, N_ * EMB_, 0);

  // 3) attention
  k_flash<<<dim3(N_ / 64, B_ * H_), 256, 0, stream>>>(Qb, Kb, Vb, Ob);

  // 4) output projection into output rows [N, 2N)
  k_gemm<<<dim3(64, 8), 256, 0, stream>>>(Ob, N_ * EMB_, w_out, b_out,
                                          out, 2 * N_ * EMB_, N_ * EMB_);
}

// Round 5
// 1411.404 us; speedup vs baseline: 1.8767x; 1.8767x over previous
//
#include <hip/hip_runtime.h>
#include <hip/hip_bf16.h>

#define B_ 4
#define N_ 2048
#define E_ 512
#define EMB_ 1024
#define H_ 8
#define D_ 128
#define KNN_ 16

typedef short short8_t __attribute__((ext_vector_type(8)));
typedef short short4_t __attribute__((ext_vector_type(4)));
typedef float float4_t __attribute__((ext_vector_type(4)));

__device__ __forceinline__ short f2bf(float f) {
  unsigned u = __float_as_uint(f);
  unsigned r = u + 0x7fffu + ((u >> 16) & 1u);   // RNE to bf16
  return (short)(r >> 16);
}

// ---------------------------------------------------------------------------
// K0: sq[b,e] = np.sum(xt*xt, -1) emulating numpy's pairwise_sum on the
// contiguous fp32 temp (verified round 4 — do not touch).
// ---------------------------------------------------------------------------
__global__ __launch_bounds__(256) void k_sqnp(const float* __restrict__ x,
                                              float* __restrict__ sq) {
  const int t = blockIdx.x * 256 + threadIdx.x;   // b*E + e
  if (t >= B_ * E_) return;
  const int b = t >> 9, e = t & (E_ - 1);
  const float* xb = x + (size_t)b * N_ * E_ + e;
  float bs[16];
  for (int blk = 0; blk < 16; blk++) {
    const float* p = xb + (size_t)blk * 128 * E_;
    float lane[16];
#pragma unroll
    for (int l = 0; l < 16; l++) {
      float pr[8];
#pragma unroll
      for (int j = 0; j < 8; j++) {
        float v = p[(size_t)(j * 16 + l) * E_];
        pr[j] = __fmul_rn(v, v);
      }
      float s01 = __fadd_rn(pr[0], pr[1]);
      float s23 = __fadd_rn(pr[2], pr[3]);
      float s45 = __fadd_rn(pr[4], pr[5]);
      float s67 = __fadd_rn(pr[6], pr[7]);
      lane[l] = __fadd_rn(__fadd_rn(s01, s23), __fadd_rn(s45, s67));
    }
    float bb[8];
#pragma unroll
    for (int l = 0; l < 8; l++) bb[l] = __fadd_rn(lane[l], lane[l + 8]);
    float cc[4];
#pragma unroll
    for (int l = 0; l < 4; l++) cc[l] = __fadd_rn(bb[l], bb[l + 4]);
    bs[blk] = __fadd_rn(__fadd_rn(cc[0], cc[1]), __fadd_rn(cc[2], cc[3]));
  }
  float t1[8], t2[4];
#pragma unroll
  for (int l = 0; l < 8; l++) t1[l] = __fadd_rn(bs[2 * l], bs[2 * l + 1]);
#pragma unroll
  for (int l = 0; l < 4; l++) t2[l] = __fadd_rn(t1[2 * l], t1[2 * l + 1]);
  sq[t] = __fadd_rn(__fadd_rn(t2[0], t2[1]), __fadd_rn(t2[2], t2[3]));
}

// ---------------------------------------------------------------------------
// K1: g[b,i,j] = einsum('ben,bfn->bef') emulating numpy's scalar sequential
// no-FMA loop (verified round 4 — do not touch).
// ---------------------------------------------------------------------------
__global__ __launch_bounds__(256) void k_gramnp(const float* __restrict__ x,
                                                float* __restrict__ g) {
  __shared__ float xi[32][36];
  __shared__ float xj[32][36];
  const int tid = threadIdx.x;
  const int i0 = blockIdx.x * 32, j0 = blockIdx.y * 32, b = blockIdx.z;
  const int il = tid & 15, jl = tid >> 4;
  const float* xb = x + (size_t)b * N_ * E_;
  float a00 = 0.f, a01 = 0.f, a10 = 0.f, a11 = 0.f;
  const int sc = tid & 31;
  const int sr0 = tid >> 5;
  for (int n0 = 0; n0 < N_; n0 += 32) {
    __syncthreads();
#pragma unroll
    for (int rr = 0; rr < 4; rr++) {
      const int nn = sr0 + rr * 8;
      xi[sc][nn] = xb[(size_t)(n0 + nn) * E_ + i0 + sc];
      xj[sc][nn] = xb[(size_t)(n0 + nn) * E_ + j0 + sc];
    }
    __syncthreads();
#pragma unroll
    for (int nn = 0; nn < 32; nn++) {
      const float va0 = xi[il][nn],      va1 = xi[il + 16][nn];
      const float vb0 = xj[jl][nn],      vb1 = xj[jl + 16][nn];
      a00 = __fadd_rn(a00, __fmul_rn(va0, vb0));
      a01 = __fadd_rn(a01, __fmul_rn(va0, vb1));
      a10 = __fadd_rn(a10, __fmul_rn(va1, vb0));
      a11 = __fadd_rn(a11, __fmul_rn(va1, vb1));
    }
  }
  float* gb = g + ((size_t)b * E_ + i0) * E_ + j0;
  gb[(size_t)il * E_ + jl]             = a00;
  gb[(size_t)il * E_ + jl + 16]        = a01;
  gb[(size_t)(il + 16) * E_ + jl]      = a10;
  gb[(size_t)(il + 16) * E_ + jl + 16] = a11;
}

// ---------------------------------------------------------------------------
// K2: top-16 smallest dist, fp32 formula, ties -> lower index (verified).
// ---------------------------------------------------------------------------
__global__ __launch_bounds__(256) void k_topk(const float* __restrict__ sq,
                                              const float* __restrict__ g,
                                              int* __restrict__ idxout) {
  const int bi = blockIdx.x;            // b*E + i
  const int b = bi >> 9, i = bi & (E_ - 1);
  const int tid = threadIdx.x;
  const float* gb = g + ((size_t)b * E_ + i) * E_;
  const float* sqb = sq + ((size_t)b << 9);
  __shared__ float val[E_];
  __shared__ float rv[256];
  __shared__ int ri[256];
  const float sqi = sqb[i];
  for (int j = tid; j < E_; j += 256) {
    val[j] = __fsub_rn(__fadd_rn(sqi, sqb[j]), __fmul_rn(2.0f, gb[j]));
  }
  __syncthreads();
  for (int t = 0; t < KNN_; t++) {
    float best = 3.0e38f; int bidx = E_;
    for (int j = tid; j < E_; j += 256) {
      float v = val[j];
      if (v < best) { best = v; bidx = j; }
    }
    rv[tid] = best; ri[tid] = bidx;
    __syncthreads();
    for (int s = 128; s > 0; s >>= 1) {
      if (tid < s) {
        float v2 = rv[tid + s]; int i2 = ri[tid + s];
        if (v2 < rv[tid] || (v2 == rv[tid] && i2 < ri[tid])) {
          rv[tid] = v2; ri[tid] = i2;
        }
      }
      __syncthreads();
    }
    if (tid == 0) {
      idxout[(size_t)bi * KNN_ + t] = ri[0];
      val[ri[0]] = 3.0e38f;
    }
    __syncthreads();
  }
}

// ---------------------------------------------------------------------------
// K3: x_knn mean + interleaved q into output's q half (verified).
// ---------------------------------------------------------------------------
__global__ __launch_bounds__(256) void k_knnmean(const float* __restrict__ x,
                                                 const int* __restrict__ idx,
                                                 float* __restrict__ out) {
  const int n = blockIdx.x, b = blockIdx.y;
  const int tid = threadIdx.x;
  __shared__ float xrow[E_];
  const float* xr = x + ((size_t)b * N_ + n) * E_;
  for (int i = tid; i < E_; i += 256) xrow[i] = xr[i];
  __syncthreads();
  float* orow = out + ((size_t)b * (2 * N_) + n) * EMB_;
  for (int i = tid; i < E_; i += 256) {
    const int* id = idx + ((size_t)b * E_ + i) * KNN_;
    float s = 0.f;
#pragma unroll
    for (int t = 0; t < KNN_; t++) s = __fadd_rn(s, xrow[id[t]]);
    float2 w; w.x = xrow[i]; w.y = s * (1.0f / 16.0f);
    *(float2*)&orow[2 * i] = w;
  }
}

// ---------------------------------------------------------------------------
// K4: fp32 projection GEMM (unchanged this round; MFMA port next).
// ---------------------------------------------------------------------------
__global__ __launch_bounds__(256) void k_gemm(const float* __restrict__ X, int xbs,
                                              const float* __restrict__ W,
                                              const float* __restrict__ bias,
                                              float* __restrict__ Y, int ybs, int yoff) {
  __shared__ float As[16][132];
  __shared__ float Bs[16][132];
  const int tid = threadIdx.x;
  const int tx = tid & 15, ty = tid >> 4;
  const int row0 = blockIdx.x * 128, col0 = blockIdx.y * 128;
  float acc[8][8];
#pragma unroll
  for (int i = 0; i < 8; i++)
#pragma unroll
    for (int j = 0; j < 8; j++) acc[i][j] = 0.f;

  const int r = tid >> 1;
  const int kk = (tid & 1) * 8;
  const int m = row0 + r, bb = m >> 11, nn = m & (N_ - 1);
  const float* xrow = X + (size_t)bb * xbs + (size_t)nn * EMB_;
  const float* wrow = W + (size_t)(col0 + r) * EMB_;

  for (int k0 = 0; k0 < EMB_; k0 += 16) {
    float4 a0 = *(const float4*)(xrow + k0 + kk);
    float4 a1 = *(const float4*)(xrow + k0 + kk + 4);
    float4 w0 = *(const float4*)(wrow + k0 + kk);
    float4 w1 = *(const float4*)(wrow + k0 + kk + 4);
    __syncthreads();
    As[kk + 0][r] = a0.x; As[kk + 1][r] = a0.y; As[kk + 2][r] = a0.z; As[kk + 3][r] = a0.w;
    As[kk + 4][r] = a1.x; As[kk + 5][r] = a1.y; As[kk + 6][r] = a1.z; As[kk + 7][r] = a1.w;
    Bs[kk + 0][r] = w0.x; Bs[kk + 1][r] = w0.y; Bs[kk + 2][r] = w0.z; Bs[kk + 3][r] = w0.w;
    Bs[kk + 4][r] = w1.x; Bs[kk + 5][r] = w1.y; Bs[kk + 6][r] = w1.z; Bs[kk + 7][r] = w1.w;
    __syncthreads();
#pragma unroll
    for (int k = 0; k < 16; k++) {
      float av[8], bv[8];
      *(float4*)&av[0] = *(const float4*)&As[k][ty * 8];
      *(float4*)&av[4] = *(const float4*)&As[k][ty * 8 + 4];
      *(float4*)&bv[0] = *(const float4*)&Bs[k][tx * 8];
      *(float4*)&bv[4] = *(const float4*)&Bs[k][tx * 8 + 4];
#pragma unroll
      for (int i = 0; i < 8; i++)
#pragma unroll
        for (int j = 0; j < 8; j++) acc[i][j] += av[i] * bv[j];
    }
  }
#pragma unroll
  for (int i = 0; i < 8; i++) {
    const int mm = row0 + ty * 8 + i;
    const int bb2 = mm >> 11, nn2 = mm & (N_ - 1);
    float* yrow = Y + (size_t)bb2 * ybs + yoff + (size_t)nn2 * EMB_ + col0 + tx * 8;
#pragma unroll
    for (int j4 = 0; j4 < 8; j4 += 4) {
      float4 o;
      o.x = acc[i][j4 + 0] + bias[col0 + tx * 8 + j4 + 0];
      o.y = acc[i][j4 + 1] + bias[col0 + tx * 8 + j4 + 1];
      o.z = acc[i][j4 + 2] + bias[col0 + tx * 8 + j4 + 2];
      o.w = acc[i][j4 + 3] + bias[col0 + tx * 8 + j4 + 3];
      *(float4*)&yrow[j4] = o;
    }
  }
}

// ---------------------------------------------------------------------------
// K5: bf16 MFMA flash attention per (b,h). 64 Q-rows/block, 4 waves x 16 rows,
// 64-key tiles. Swapped QK^T: S^T = mfma(K_frag, Q_frag) puts q = lane&15 ->
// softmax is in-lane (16 vals) + shfl_xor(16,32). PV as O^T = V^T*P^T keeps
// alpha/l lane-local. K key-major, V d-major (transposed), P per-wave, all
// XOR-swizzled (idx ^= (row&7)<<3 in shorts) for conflict-free ds_read_b128.
// ---------------------------------------------------------------------------
__global__ __launch_bounds__(256) void k_flash_mfma(const float* __restrict__ Qg,
                                                    const float* __restrict__ Kg,
                                                    const float* __restrict__ Vg,
                                                    float* __restrict__ Og) {
  __shared__ short Ks[64 * 128];    // [key][d]  swizzled
  __shared__ short Vs[128 * 64];    // [d][key]  swizzled (transposed)
  __shared__ short Ps[4][16 * 64];  // per-wave [q][key] swizzled
  const int tid = threadIdx.x;
  const int w = tid >> 6, l = tid & 63;
  const int lg = l >> 4, lq = l & 15;
  const int rt = blockIdx.x, bh = blockIdx.y;
  const int b = bh >> 3, h = bh & 7;
  const float scale = 0.08838834764831845f;  // 1/sqrt(128)
  const size_t bhoff = ((size_t)b * N_) * EMB_ + (size_t)h * D_;
  const int qsw = (lq & 7) << 3;

  // Q fragments: qf[kk][j] = Q[q0+lq][kk*32 + lg*8 + j] * scale  (bf16)
  short8_t qf[4];
  {
    const float* qrow = Qg + bhoff + (size_t)(rt * 64 + w * 16 + lq) * EMB_;
#pragma unroll
    for (int kk = 0; kk < 4; kk++) {
      const float* p = qrow + kk * 32 + lg * 8;
      float4 v0 = *(const float4*)p;
      float4 v1 = *(const float4*)(p + 4);
      short8_t q;
      q[0] = f2bf(v0.x * scale); q[1] = f2bf(v0.y * scale);
      q[2] = f2bf(v0.z * scale); q[3] = f2bf(v0.w * scale);
      q[4] = f2bf(v1.x * scale); q[5] = f2bf(v1.y * scale);
      q[6] = f2bf(v1.z * scale); q[7] = f2bf(v1.w * scale);
      qf[kk] = q;
    }
  }

  float4_t oacc[8];
#pragma unroll
  for (int mc = 0; mc < 8; mc++) {
    oacc[mc][0] = 0.f; oacc[mc][1] = 0.f; oacc[mc][2] = 0.f; oacc[mc][3] = 0.f;
  }
  float m = -3.0e38f, lsum = 0.f;

  for (int kt = 0; kt < N_ / 64; kt++) {
    __syncthreads();   // previous tile's LDS reads done
    // ---- stage K (key-major, bf16, swizzled); coalesced fp32 reads
    {
      const float* Kt = Kg + bhoff + (size_t)(kt * 64) * EMB_;
      const int row = tid >> 3;            // 0..31
      const int c0 = (tid & 7) * 16;
#pragma unroll
      for (int hh = 0; hh < 2; hh++) {
        const int r = row + hh * 32;
        const float* src = Kt + (size_t)r * EMB_ + c0;
        float4 a = *(const float4*)(src);
        float4 b2 = *(const float4*)(src + 4);
        float4 c2 = *(const float4*)(src + 8);
        float4 d2 = *(const float4*)(src + 12);
        short8_t lo, hi;
        lo[0] = f2bf(a.x);  lo[1] = f2bf(a.y);  lo[2] = f2bf(a.z);  lo[3] = f2bf(a.w);
        lo[4] = f2bf(b2.x); lo[5] = f2bf(b2.y); lo[6] = f2bf(b2.z); lo[7] = f2bf(b2.w);
        hi[0] = f2bf(c2.x); hi[1] = f2bf(c2.y); hi[2] = f2bf(c2.z); hi[3] = f2bf(c2.w);
        hi[4] = f2bf(d2.x); hi[5] = f2bf(d2.y); hi[6] = f2bf(d2.z); hi[7] = f2bf(d2.w);
        const int sw = (r & 7) << 3;
        *(short8_t*)&Ks[r * 128 + (c0 ^ sw)] = lo;
        *(short8_t*)&Ks[r * 128 + ((c0 + 8) ^ sw)] = hi;
      }
    }
    // ---- stage V (d-major transpose, bf16, swizzled); coalesced fp32 reads
    {
      const float* Vt = Vg + bhoff + (size_t)(kt * 64) * EMB_;
      const int d0 = (tid & 31) * 4;
#pragma unroll
      for (int ii = 0; ii < 8; ii++) {
        const int key = ii * 8 + (tid >> 5);
        float4 v = *(const float4*)(Vt + (size_t)key * EMB_ + d0);
        Vs[(d0 + 0) * 64 + (key ^ (((d0 + 0) & 7) << 3))] = f2bf(v.x);
        Vs[(d0 + 1) * 64 + (key ^ (((d0 + 1) & 7) << 3))] = f2bf(v.y);
        Vs[(d0 + 2) * 64 + (key ^ (((d0 + 2) & 7) << 3))] = f2bf(v.z);
        Vs[(d0 + 3) * 64 + (key ^ (((d0 + 3) & 7) << 3))] = f2bf(v.w);
      }
    }
    __syncthreads();

    // ---- S^T = K . Q^T : sc[c][j] = S[q=lq][key = c*16 + lg*4 + j]
    float4_t sc[4];
#pragma unroll
    for (int c = 0; c < 4; c++) {
      sc[c][0] = 0.f; sc[c][1] = 0.f; sc[c][2] = 0.f; sc[c][3] = 0.f;
      const int krow = c * 16 + lq;        // (krow&7) == (lq&7)
#pragma unroll
      for (int kk = 0; kk < 4; kk++) {
        short8_t kf = *(const short8_t*)&Ks[krow * 128 + ((kk * 32 + lg * 8) ^ qsw)];
        sc[c] = __builtin_amdgcn_mfma_f32_16x16x32_bf16(kf, qf[kk], sc[c], 0, 0, 0);
      }
    }

    // ---- online softmax (row = q = lq, lane-local + 2 shuffles over lg)
    float tm = sc[0][0];
#pragma unroll
    for (int c = 0; c < 4; c++)
#pragma unroll
      for (int j = 0; j < 4; j++) tm = fmaxf(tm, sc[c][j]);
    tm = fmaxf(tm, __shfl_xor(tm, 16));
    tm = fmaxf(tm, __shfl_xor(tm, 32));
    const float mn = fmaxf(m, tm);
    const float alpha = __expf(m - mn);
    m = mn;
    float ps = 0.f;
    short4_t pb[4];
#pragma unroll
    for (int c = 0; c < 4; c++) {
#pragma unroll
      for (int j = 0; j < 4; j++) {
        float p = __expf(sc[c][j] - mn);
        ps += p;
        pb[c][j] = f2bf(p);
      }
    }
    ps += __shfl_xor(ps, 16);
    ps += __shfl_xor(ps, 32);
    lsum = lsum * alpha + ps;

    // ---- write P (per-wave region, [q][key] swizzled); no barrier needed
#pragma unroll
    for (int c = 0; c < 4; c++) {
      *(short4_t*)&Ps[w][lq * 64 + ((c * 16 + lg * 4) ^ qsw)] = pb[c];
    }

    // ---- rescale O, then O^T += V^T . P^T
#pragma unroll
    for (int mc = 0; mc < 8; mc++) {
      oacc[mc][0] *= alpha; oacc[mc][1] *= alpha;
      oacc[mc][2] *= alpha; oacc[mc][3] *= alpha;
    }
#pragma unroll
    for (int kk = 0; kk < 2; kk++) {
      short8_t pf = *(const short8_t*)&Ps[w][lq * 64 + ((kk * 32 + lg * 8) ^ qsw)];
#pragma unroll
      for (int mc = 0; mc < 8; mc++) {
        const int d = mc * 16 + lq;        // (d&7) == (lq&7)
        short8_t vf = *(const short8_t*)&Vs[d * 64 + ((kk * 32 + lg * 8) ^ qsw)];
        oacc[mc] = __builtin_amdgcn_mfma_f32_16x16x32_bf16(vf, pf, oacc[mc], 0, 0, 0);
      }
    }
  }

  // ---- epilogue: O[q][d] = oacc / lsum ; d = mc*16 + lg*4 + j, q = lq
  const float linv = 1.0f / lsum;
  float* orow = Og + bhoff + (size_t)(rt * 64 + w * 16 + lq) * EMB_;
#pragma unroll
  for (int mc = 0; mc < 8; mc++) {
    float4 o;
    o.x = oacc[mc][0] * linv; o.y = oacc[mc][1] * linv;
    o.z = oacc[mc][2] * linv; o.w = oacc[mc][3] * linv;
    *(float4*)&orow[mc * 16 + lg * 4] = o;
  }
}

// ---------------------------------------------------------------------------
extern "C" void kernel_launch(void* const* d_in, const int* in_sizes, int n_in,
                              void* d_out, int out_size, void* d_ws, size_t ws_size,
                              hipStream_t stream) {
  const float* x     = (const float*)d_in[0];
  const float* x_enc = (const float*)d_in[1];
  const float* w_in  = (const float*)d_in[2];
  const float* b_in  = (const float*)d_in[3];
  const float* w_out = (const float*)d_in[4];
  const float* b_out = (const float*)d_in[5];
  float* out = (float*)d_out;
  float* ws  = (float*)d_ws;

  const size_t szG   = (size_t)B_ * E_ * E_;
  const size_t szSq  = (size_t)B_ * E_;
  const size_t szIdx = (size_t)B_ * E_ * KNN_;
  const size_t szBuf = (size_t)B_ * N_ * EMB_;

  float* g   = ws;
  float* sqv = ws + szG;
  int*   idx = (int*)(ws + szG + szSq);
  float* Qb  = ws + szG + szSq + szIdx;
  float* Kb  = Qb + szBuf;
  float* Vb  = Kb + szBuf;
  const size_t needFull = (szG + szSq + szIdx + 4 * szBuf) * sizeof(float);
  float* Ob = (ws_size >= needFull) ? (Vb + szBuf) : Qb;  // alias-safe (disjoint per block)

  // 1) kNN emulating the numpy reference's fp32 numerics exactly
  k_sqnp<<<dim3((B_ * E_ + 255) / 256), 256, 0, stream>>>(x, sqv);
  k_gramnp<<<dim3(E_ / 32, E_ / 32, B_), 256, 0, stream>>>(x, g);
  k_topk<<<dim3(B_ * E_), 256, 0, stream>>>(sqv, g, idx);
  k_knnmean<<<dim3(N_, B_), 256, 0, stream>>>(x, idx, out);

  // 2) projections (fp32 this round)
  k_gemm<<<dim3(64, 8), 256, 0, stream>>>(out, 2 * N_ * EMB_, w_in, b_in,
                                          Qb, N_ * EMB_, 0);
  k_gemm<<<dim3(64, 8), 256, 0, stream>>>(x_enc, N_ * EMB_, w_in + (size_t)EMB_ * EMB_,
                                          b_in + EMB_, Kb, N_ * EMB_, 0);
  k_gemm<<<dim3(64, 8), 256, 0, stream>>>(x_enc, N_ * EMB_, w_in + 2 * (size_t)EMB_ * EMB_,
                                          b_in + 2 * EMB_, Vb, N_ * EMB_, 0);

  // 3) attention — bf16 MFMA flash
  k_flash_mfma<<<dim3(N_ / 64, B_ * H_), 256, 0, stream>>>(Qb, Kb, Vb, Ob);

  // 4) output projection into output rows [N, 2N)
  k_gemm<<<dim3(64, 8), 256, 0, stream>>>(Ob, N_ * EMB_, w_out, b_out,
                                          out, 2 * N_ * EMB_, N_ * EMB_);
}

// Round 6
// 445.655 us; speedup vs baseline: 5.9435x; 3.1670x over previous
//
#include <hip/hip_runtime.h>
#include <hip/hip_bf16.h>

#define B_ 4
#define N_ 2048
#define E_ 512
#define EMB_ 1024
#define H_ 8
#define D_ 128
#define KNN_ 16

typedef short short8_t __attribute__((ext_vector_type(8)));
typedef short short4_t __attribute__((ext_vector_type(4)));
typedef float float4_t __attribute__((ext_vector_type(4)));

__device__ __forceinline__ short f2bf(float f) {
  unsigned u = __float_as_uint(f);
  unsigned r = u + 0x7fffu + ((u >> 16) & 1u);   // RNE to bf16
  return (short)(r >> 16);
}

// ---------------------------------------------------------------------------
// K0: sq[b,e] = np.sum(xt*xt, -1) emulating numpy pairwise_sum (verified r4).
// ---------------------------------------------------------------------------
__global__ __launch_bounds__(256) void k_sqnp(const float* __restrict__ x,
                                              float* __restrict__ sq) {
  const int t = blockIdx.x * 256 + threadIdx.x;   // b*E + e
  if (t >= B_ * E_) return;
  const int b = t >> 9, e = t & (E_ - 1);
  const float* xb = x + (size_t)b * N_ * E_ + e;
  float bs[16];
  for (int blk = 0; blk < 16; blk++) {
    const float* p = xb + (size_t)blk * 128 * E_;
    float lane[16];
#pragma unroll
    for (int l = 0; l < 16; l++) {
      float pr[8];
#pragma unroll
      for (int j = 0; j < 8; j++) {
        float v = p[(size_t)(j * 16 + l) * E_];
        pr[j] = __fmul_rn(v, v);
      }
      float s01 = __fadd_rn(pr[0], pr[1]);
      float s23 = __fadd_rn(pr[2], pr[3]);
      float s45 = __fadd_rn(pr[4], pr[5]);
      float s67 = __fadd_rn(pr[6], pr[7]);
      lane[l] = __fadd_rn(__fadd_rn(s01, s23), __fadd_rn(s45, s67));
    }
    float bb[8];
#pragma unroll
    for (int l = 0; l < 8; l++) bb[l] = __fadd_rn(lane[l], lane[l + 8]);
    float cc[4];
#pragma unroll
    for (int l = 0; l < 4; l++) cc[l] = __fadd_rn(bb[l], bb[l + 4]);
    bs[blk] = __fadd_rn(__fadd_rn(cc[0], cc[1]), __fadd_rn(cc[2], cc[3]));
  }
  float t1[8], t2[4];
#pragma unroll
  for (int l = 0; l < 8; l++) t1[l] = __fadd_rn(bs[2 * l], bs[2 * l + 1]);
#pragma unroll
  for (int l = 0; l < 4; l++) t2[l] = __fadd_rn(t1[2 * l], t1[2 * l + 1]);
  sq[t] = __fadd_rn(__fadd_rn(t2[0], t2[1]), __fadd_rn(t2[2], t2[3]));
}

// ---------------------------------------------------------------------------
// K1: g = einsum('ben,bfn->bef') emulating numpy scalar no-FMA loop (verified r4).
// ---------------------------------------------------------------------------
__global__ __launch_bounds__(256) void k_gramnp(const float* __restrict__ x,
                                                float* __restrict__ g) {
  __shared__ float xi[32][36];
  __shared__ float xj[32][36];
  const int tid = threadIdx.x;
  const int i0 = blockIdx.x * 32, j0 = blockIdx.y * 32, b = blockIdx.z;
  const int il = tid & 15, jl = tid >> 4;
  const float* xb = x + (size_t)b * N_ * E_;
  float a00 = 0.f, a01 = 0.f, a10 = 0.f, a11 = 0.f;
  const int sc = tid & 31;
  const int sr0 = tid >> 5;
  for (int n0 = 0; n0 < N_; n0 += 32) {
    __syncthreads();
#pragma unroll
    for (int rr = 0; rr < 4; rr++) {
      const int nn = sr0 + rr * 8;
      xi[sc][nn] = xb[(size_t)(n0 + nn) * E_ + i0 + sc];
      xj[sc][nn] = xb[(size_t)(n0 + nn) * E_ + j0 + sc];
    }
    __syncthreads();
#pragma unroll
    for (int nn = 0; nn < 32; nn++) {
      const float va0 = xi[il][nn],      va1 = xi[il + 16][nn];
      const float vb0 = xj[jl][nn],      vb1 = xj[jl + 16][nn];
      a00 = __fadd_rn(a00, __fmul_rn(va0, vb0));
      a01 = __fadd_rn(a01, __fmul_rn(va0, vb1));
      a10 = __fadd_rn(a10, __fmul_rn(va1, vb0));
      a11 = __fadd_rn(a11, __fmul_rn(va1, vb1));
    }
  }
  float* gb = g + ((size_t)b * E_ + i0) * E_ + j0;
  gb[(size_t)il * E_ + jl]             = a00;
  gb[(size_t)il * E_ + jl + 16]        = a01;
  gb[(size_t)(il + 16) * E_ + jl]      = a10;
  gb[(size_t)(il + 16) * E_ + jl + 16] = a11;
}

// ---------------------------------------------------------------------------
// K2: top-16 smallest dist, fp32 formula, ties -> lower index (verified r4).
// ---------------------------------------------------------------------------
__global__ __launch_bounds__(256) void k_topk(const float* __restrict__ sq,
                                              const float* __restrict__ g,
                                              int* __restrict__ idxout) {
  const int bi = blockIdx.x;            // b*E + i
  const int b = bi >> 9, i = bi & (E_ - 1);
  const int tid = threadIdx.x;
  const float* gb = g + ((size_t)b * E_ + i) * E_;
  const float* sqb = sq + ((size_t)b << 9);
  __shared__ float val[E_];
  __shared__ float rv[256];
  __shared__ int ri[256];
  const float sqi = sqb[i];
  for (int j = tid; j < E_; j += 256) {
    val[j] = __fsub_rn(__fadd_rn(sqi, sqb[j]), __fmul_rn(2.0f, gb[j]));
  }
  __syncthreads();
  for (int t = 0; t < KNN_; t++) {
    float best = 3.0e38f; int bidx = E_;
    for (int j = tid; j < E_; j += 256) {
      float v = val[j];
      if (v < best) { best = v; bidx = j; }
    }
    rv[tid] = best; ri[tid] = bidx;
    __syncthreads();
    for (int s = 128; s > 0; s >>= 1) {
      if (tid < s) {
        float v2 = rv[tid + s]; int i2 = ri[tid + s];
        if (v2 < rv[tid] || (v2 == rv[tid] && i2 < ri[tid])) {
          rv[tid] = v2; ri[tid] = i2;
        }
      }
      __syncthreads();
    }
    if (tid == 0) {
      idxout[(size_t)bi * KNN_ + t] = ri[0];
      val[ri[0]] = 3.0e38f;
    }
    __syncthreads();
  }
}

// ---------------------------------------------------------------------------
// K3: x_knn mean + interleaved q into output's q half (verified r4).
// ---------------------------------------------------------------------------
__global__ __launch_bounds__(256) void k_knnmean(const float* __restrict__ x,
                                                 const int* __restrict__ idx,
                                                 float* __restrict__ out) {
  const int n = blockIdx.x, b = blockIdx.y;
  const int tid = threadIdx.x;
  __shared__ float xrow[E_];
  const float* xr = x + ((size_t)b * N_ + n) * E_;
  for (int i = tid; i < E_; i += 256) xrow[i] = xr[i];
  __syncthreads();
  float* orow = out + ((size_t)b * (2 * N_) + n) * EMB_;
  for (int i = tid; i < E_; i += 256) {
    const int* id = idx + ((size_t)b * E_ + i) * KNN_;
    float s = 0.f;
#pragma unroll
    for (int t = 0; t < KNN_; t++) s = __fadd_rn(s, xrow[id[t]]);
    float2 w; w.x = xrow[i]; w.y = s * (1.0f / 16.0f);
    *(float2*)&orow[2 * i] = w;
  }
}

// ---------------------------------------------------------------------------
// cvt: fp32 -> bf16, 8 elems/thread, contiguous.
// ---------------------------------------------------------------------------
__global__ __launch_bounds__(256) void k_cvt(const float* __restrict__ src,
                                             short* __restrict__ dst, int n8) {
  const int t = blockIdx.x * 256 + threadIdx.x;
  if (t >= n8) return;
  const float* s = src + (size_t)t * 8;
  float4 a = *(const float4*)s, b = *(const float4*)(s + 4);
  short8_t v;
  v[0] = f2bf(a.x); v[1] = f2bf(a.y); v[2] = f2bf(a.z); v[3] = f2bf(a.w);
  v[4] = f2bf(b.x); v[5] = f2bf(b.y); v[6] = f2bf(b.z); v[7] = f2bf(b.w);
  *(short8_t*)(dst + (size_t)t * 8) = v;
}

// cvt of q (strided: rows live in out's q-half with batch stride 2N*EMB)
__global__ __launch_bounds__(256) void k_cvt_q(const float* __restrict__ outq,
                                               short* __restrict__ dst) {
  const int t = blockIdx.x * 256 + threadIdx.x;  // chunk of 8, 8192*128 total
  const int row = t >> 7, c = (t & 127) * 8;
  const int b = row >> 11, n = row & (N_ - 1);
  const float* s = outq + ((size_t)b * 2 * N_ + n) * EMB_ + c;
  float4 a = *(const float4*)s, bb = *(const float4*)(s + 4);
  short8_t v;
  v[0] = f2bf(a.x);  v[1] = f2bf(a.y);  v[2] = f2bf(a.z);  v[3] = f2bf(a.w);
  v[4] = f2bf(bb.x); v[5] = f2bf(bb.y); v[6] = f2bf(bb.z); v[7] = f2bf(bb.w);
  *(short8_t*)(dst + (size_t)row * EMB_ + c) = v;
}

// ---------------------------------------------------------------------------
// K4: bf16 MFMA projection GEMM. Y[m,o] = sum_k X[m,k]*W[o,k] + bias[o].
// 128x128 tile, BK=64, 4 waves (2x2), 4x4 16x16x32 frags per wave.
// LDS XOR swizzle (c*8)^((r&7)<<3) -> optimal banks for stage-write & frag-read.
// MODE 0: bf16 row-major [8192][1024]; MODE 1: fp32 into out rows [N,2N);
// MODE 2: bf16 TRANSPOSED [b][col][n] (V^T for flash).
// ---------------------------------------------------------------------------
template<int MODE>
__global__ __launch_bounds__(256) void k_gemm_bf16(
    const short* __restrict__ X, const short* __restrict__ W,
    const float* __restrict__ bias, short* __restrict__ Yb,
    float* __restrict__ Yf) {
  __shared__ __align__(16) short As[128 * 64];
  __shared__ __align__(16) short Bs[128 * 64];
  const int tid = threadIdx.x;
  const int row0 = blockIdx.x * 128, col0 = blockIdx.y * 128;
  const int l = tid & 63, lg = l >> 4, lq = l & 15;
  const int w = tid >> 6, wm = w >> 1, wn = w & 1;
  float4_t acc[4][4];
#pragma unroll
  for (int i = 0; i < 4; i++)
#pragma unroll
    for (int j = 0; j < 4; j++) {
      acc[i][j][0] = 0.f; acc[i][j][1] = 0.f; acc[i][j][2] = 0.f; acc[i][j][3] = 0.f;
    }

  int rr_[4], cc_[4];
#pragma unroll
  for (int ii = 0; ii < 4; ii++) {
    const int cid = ii * 256 + tid;
    rr_[ii] = cid >> 3; cc_[ii] = cid & 7;
  }
  short8_t ar[4], br[4];
#pragma unroll
  for (int ii = 0; ii < 4; ii++) {
    ar[ii] = *(const short8_t*)(X + (size_t)(row0 + rr_[ii]) * EMB_ + cc_[ii] * 8);
    br[ii] = *(const short8_t*)(W + (size_t)(col0 + rr_[ii]) * EMB_ + cc_[ii] * 8);
  }

  for (int kt = 0; kt < 16; kt++) {
    __syncthreads();                 // prev iter's frag reads done
#pragma unroll
    for (int ii = 0; ii < 4; ii++) {
      const int idx = rr_[ii] * 64 + ((cc_[ii] * 8) ^ ((rr_[ii] & 7) << 3));
      *(short8_t*)&As[idx] = ar[ii];
      *(short8_t*)&Bs[idx] = br[ii];
    }
    __syncthreads();
    if (kt < 15) {                   // prefetch next tile (hides HBM under MFMA)
#pragma unroll
      for (int ii = 0; ii < 4; ii++) {
        ar[ii] = *(const short8_t*)(X + (size_t)(row0 + rr_[ii]) * EMB_ + (kt + 1) * 64 + cc_[ii] * 8);
        br[ii] = *(const short8_t*)(W + (size_t)(col0 + rr_[ii]) * EMB_ + (kt + 1) * 64 + cc_[ii] * 8);
      }
    }
#pragma unroll
    for (int kk = 0; kk < 2; kk++) {
      short8_t af[4], bf[4];
#pragma unroll
      for (int mi = 0; mi < 4; mi++) {
        const int r = wm * 64 + mi * 16 + lq;
        af[mi] = *(const short8_t*)&As[r * 64 + ((kk * 32 + lg * 8) ^ ((r & 7) << 3))];
      }
#pragma unroll
      for (int ni = 0; ni < 4; ni++) {
        const int r = wn * 64 + ni * 16 + lq;
        bf[ni] = *(const short8_t*)&Bs[r * 64 + ((kk * 32 + lg * 8) ^ ((r & 7) << 3))];
      }
#pragma unroll
      for (int mi = 0; mi < 4; mi++)
#pragma unroll
        for (int ni = 0; ni < 4; ni++)
          acc[mi][ni] = __builtin_amdgcn_mfma_f32_16x16x32_bf16(af[mi], bf[ni], acc[mi][ni], 0, 0, 0);
    }
  }
  // epilogue: D col = lane&15 (=n), row = lg*4+reg (m within 16)  [m89-verified]
#pragma unroll
  for (int ni = 0; ni < 4; ni++) {
    const int col = col0 + wn * 64 + ni * 16 + lq;
    const float bv = bias[col];
#pragma unroll
    for (int mi = 0; mi < 4; mi++) {
#pragma unroll
      for (int j = 0; j < 4; j++) {
        const int m = row0 + wm * 64 + mi * 16 + lg * 4 + j;
        const float v = acc[mi][ni][j] + bv;
        if (MODE == 0) {
          Yb[(size_t)m * EMB_ + col] = f2bf(v);
        } else if (MODE == 1) {
          const int b2 = m >> 11, n2 = m & (N_ - 1);
          Yf[((size_t)b2 * 2 * N_ + N_ + n2) * EMB_ + col] = v;
        } else {
          const int b2 = m >> 11, n2 = m & (N_ - 1);
          Yb[((size_t)b2 * EMB_ + col) * N_ + n2] = f2bf(v);
        }
      }
    }
  }
}

// ---------------------------------------------------------------------------
// K5: bf16 flash attention. Q,K row-major bf16 [8192][1024]; V passed as V^T
// [b][col][n] so V staging == K staging (conflict-free, no LDS transpose).
// Swapped QK^T -> lane-local softmax; PV via Ps per-wave LDS; O out in bf16.
// XCD-aware block remap: same-bh blocks land on one XCD for K/V L2 reuse.
// ---------------------------------------------------------------------------
__global__ __launch_bounds__(256) void k_flash_bf16(
    const short* __restrict__ Qg, const short* __restrict__ Kg,
    const short* __restrict__ Vtg, short* __restrict__ Og) {
  __shared__ __align__(16) short Ks[64 * 128];   // [key][d] swizzled
  __shared__ __align__(16) short Vs[128 * 64];   // [d][key] swizzled (from V^T)
  __shared__ __align__(16) short Ps[4][16 * 64]; // per-wave [q][key] swizzled
  const int tid = threadIdx.x;
  const int w = tid >> 6, l = tid & 63, lg = l >> 4, lq = l & 15;
  // 1024 blocks = 8 xcd * 4 bh * 32 rt  (dispatch round-robins XCDs)
  const int bid = blockIdx.x;
  const int bh = (bid & 7) * 4 + ((bid >> 3) >> 5);
  const int rt = (bid >> 3) & 31;
  const int b = bh >> 3, h = bh & 7;
  const float scale = 0.08838834764831845f;  // 1/sqrt(128), applied post-QK^T
  const size_t bhoff = (size_t)b * N_ * EMB_ + (size_t)h * D_;
  const int qsw = (lq & 7) << 3;

  short8_t qf[4];
  {
    const short* qrow = Qg + bhoff + (size_t)(rt * 64 + w * 16 + lq) * EMB_;
#pragma unroll
    for (int kk = 0; kk < 4; kk++)
      qf[kk] = *(const short8_t*)(qrow + kk * 32 + lg * 8);
  }
  float4_t oacc[8];
#pragma unroll
  for (int mc = 0; mc < 8; mc++) {
    oacc[mc][0] = 0.f; oacc[mc][1] = 0.f; oacc[mc][2] = 0.f; oacc[mc][3] = 0.f;
  }
  float m = -3.0e38f, lsum = 0.f;

  const short* Vbase = Vtg + (size_t)b * EMB_ * N_ + (size_t)(h * D_) * N_;

  for (int kt = 0; kt < N_ / 64; kt++) {
    __syncthreads();                 // prev tile's LDS reads done
    const short* Kt = Kg + bhoff + (size_t)(kt * 64) * EMB_;
    const short* Vt = Vbase + kt * 64;
#pragma unroll
    for (int ii = 0; ii < 4; ii++) {
      const int cid = ii * 256 + tid;
      {  // K: 64 rows x 16 chunks
        const int r = cid >> 4, c = cid & 15;
        *(short8_t*)&Ks[r * 128 + ((c * 8) ^ ((r & 7) << 3))] =
            *(const short8_t*)(Kt + (size_t)r * EMB_ + c * 8);
      }
      {  // V^T: 128 rows x 8 chunks (row stride N_)
        const int r = cid >> 3, c = cid & 7;
        *(short8_t*)&Vs[r * 64 + ((c * 8) ^ ((r & 7) << 3))] =
            *(const short8_t*)(Vt + (size_t)r * N_ + c * 8);
      }
    }
    __syncthreads();

    // S^T = K . Q^T : sc[c][j] = S[q=lq][key = c*16 + lg*4 + j]
    float4_t sc[4];
#pragma unroll
    for (int c = 0; c < 4; c++) {
      sc[c][0] = 0.f; sc[c][1] = 0.f; sc[c][2] = 0.f; sc[c][3] = 0.f;
      const int krow = c * 16 + lq;       // (krow&7)==(lq&7) -> qsw
#pragma unroll
      for (int kk = 0; kk < 4; kk++) {
        short8_t kf = *(const short8_t*)&Ks[krow * 128 + ((kk * 32 + lg * 8) ^ qsw)];
        sc[c] = __builtin_amdgcn_mfma_f32_16x16x32_bf16(kf, qf[kk], sc[c], 0, 0, 0);
      }
    }

    // online softmax (scale applied here, fp32)
    float tm = -3.0e38f;
#pragma unroll
    for (int c = 0; c < 4; c++)
#pragma unroll
      for (int j = 0; j < 4; j++) { sc[c][j] *= scale; tm = fmaxf(tm, sc[c][j]); }
    tm = fmaxf(tm, __shfl_xor(tm, 16));
    tm = fmaxf(tm, __shfl_xor(tm, 32));
    const float mn = fmaxf(m, tm);
    const float alpha = __expf(m - mn);
    m = mn;
    float ps = 0.f;
    short4_t pb[4];
#pragma unroll
    for (int c = 0; c < 4; c++) {
#pragma unroll
      for (int j = 0; j < 4; j++) {
        float p = __expf(sc[c][j] - mn);
        ps += p;
        pb[c][j] = f2bf(p);
      }
    }
    ps += __shfl_xor(ps, 16);
    ps += __shfl_xor(ps, 32);
    lsum = lsum * alpha + ps;

#pragma unroll
    for (int c = 0; c < 4; c++)
      *(short4_t*)&Ps[w][lq * 64 + ((c * 16 + lg * 4) ^ qsw)] = pb[c];

#pragma unroll
    for (int mc = 0; mc < 8; mc++) {
      oacc[mc][0] *= alpha; oacc[mc][1] *= alpha;
      oacc[mc][2] *= alpha; oacc[mc][3] *= alpha;
    }
#pragma unroll
    for (int kk = 0; kk < 2; kk++) {
      short8_t pf = *(const short8_t*)&Ps[w][lq * 64 + ((kk * 32 + lg * 8) ^ qsw)];
#pragma unroll
      for (int mc = 0; mc < 8; mc++) {
        const int dd = mc * 16 + lq;
        short8_t vf = *(const short8_t*)&Vs[dd * 64 + ((kk * 32 + lg * 8) ^ qsw)];
        oacc[mc] = __builtin_amdgcn_mfma_f32_16x16x32_bf16(vf, pf, oacc[mc], 0, 0, 0);
      }
    }
  }

  const float linv = 1.0f / lsum;
  short* orow = Og + bhoff + (size_t)(rt * 64 + w * 16 + lq) * EMB_;
#pragma unroll
  for (int mc = 0; mc < 8; mc++) {
    short4_t o;
    o[0] = f2bf(oacc[mc][0] * linv); o[1] = f2bf(oacc[mc][1] * linv);
    o[2] = f2bf(oacc[mc][2] * linv); o[3] = f2bf(oacc[mc][3] * linv);
    *(short4_t*)&orow[mc * 16 + lg * 4] = o;
  }
}

// ---------------------------------------------------------------------------
extern "C" void kernel_launch(void* const* d_in, const int* in_sizes, int n_in,
                              void* d_out, int out_size, void* d_ws, size_t ws_size,
                              hipStream_t stream) {
  const float* x     = (const float*)d_in[0];
  const float* x_enc = (const float*)d_in[1];
  const float* w_in  = (const float*)d_in[2];
  const float* b_in  = (const float*)d_in[3];
  const float* w_out = (const float*)d_in[4];
  const float* b_out = (const float*)d_in[5];
  float* out = (float*)d_out;
  char* wsb = (char*)d_ws;

  const size_t oG   = 0;
  const size_t oSq  = oG + (size_t)B_ * E_ * E_ * 4;
  const size_t oIdx = oSq + (size_t)B_ * E_ * 4;
  const size_t oXq  = (oIdx + (size_t)B_ * E_ * KNN_ * 4 + 255) & ~(size_t)255;
  const size_t sB   = (size_t)B_ * N_ * EMB_ * 2;     // 16 MB bf16 buffer
  const size_t oXe  = oXq + sB;
  const size_t oWin = oXe + sB;
  const size_t oWo  = oWin + 3ull * EMB_ * EMB_ * 2;
  const size_t oQ   = oWo + (size_t)EMB_ * EMB_ * 2;
  const size_t oK   = oQ + sB;
  const size_t oV   = oK + sB;
  const size_t oO   = oV + sB;
  const size_t need = oO + sB;

  float* g    = (float*)(wsb + oG);
  float* sqv  = (float*)(wsb + oSq);
  int*   idx  = (int*)(wsb + oIdx);
  short* Xq   = (short*)(wsb + oXq);
  short* Xe   = (short*)(wsb + oXe);
  short* Win  = (short*)(wsb + oWin);
  short* Wo   = (short*)(wsb + oWo);
  short* Qb   = (short*)(wsb + oQ);
  short* Kb   = (short*)(wsb + oK);
  short* Vb   = (short*)(wsb + oV);
  // Fallback: alias O onto Q (safe: each flash block writes exactly the
  // Q region it alone reads, and Q is register-loaded before any O write).
  short* Ob   = (ws_size >= need) ? (short*)(wsb + oO) : Qb;

  // 1) kNN emulating the numpy reference's fp32 numerics exactly
  k_sqnp<<<dim3((B_ * E_ + 255) / 256), 256, 0, stream>>>(x, sqv);
  k_gramnp<<<dim3(E_ / 32, E_ / 32, B_), 256, 0, stream>>>(x, g);
  k_topk<<<dim3(B_ * E_), 256, 0, stream>>>(sqv, g, idx);
  k_knnmean<<<dim3(N_, B_), 256, 0, stream>>>(x, idx, out);

  // 2) bf16 conversions
  k_cvt<<<dim3(4096), 256, 0, stream>>>(x_enc, Xe, B_ * N_ * EMB_ / 8);
  k_cvt<<<dim3(1536), 256, 0, stream>>>(w_in, Win, 3 * EMB_ * EMB_ / 8);
  k_cvt<<<dim3(512), 256, 0, stream>>>(w_out, Wo, EMB_ * EMB_ / 8);
  k_cvt_q<<<dim3(4096), 256, 0, stream>>>(out, Xq);

  // 3) projections (bf16 MFMA); V written transposed for flash
  k_gemm_bf16<0><<<dim3(64, 8), 256, 0, stream>>>(Xq, Win, b_in, Qb, nullptr);
  k_gemm_bf16<0><<<dim3(64, 8), 256, 0, stream>>>(Xe, Win + (size_t)EMB_ * EMB_,
                                                  b_in + EMB_, Kb, nullptr);
  k_gemm_bf16<2><<<dim3(64, 8), 256, 0, stream>>>(Xe, Win + 2ull * EMB_ * EMB_,
                                                  b_in + 2 * EMB_, Vb, nullptr);

  // 4) attention (bf16 MFMA flash, V^T input)
  k_flash_bf16<<<dim3(1024), 256, 0, stream>>>(Qb, Kb, Vb, Ob);

  // 5) output projection -> fp32 into out rows [N, 2N)
  k_gemm_bf16<1><<<dim3(64, 8), 256, 0, stream>>>(Ob, Wo, b_out, nullptr, out);
}

// Round 7
// 397.182 us; speedup vs baseline: 6.6688x; 1.1220x over previous
//
#include <hip/hip_runtime.h>
#include <hip/hip_bf16.h>

#define B_ 4
#define N_ 2048
#define E_ 512
#define EMB_ 1024
#define H_ 8
#define D_ 128
#define KNN_ 16

typedef short short8_t __attribute__((ext_vector_type(8)));
typedef short short4_t __attribute__((ext_vector_type(4)));
typedef float float4_t __attribute__((ext_vector_type(4)));

__device__ __forceinline__ short f2bf(float f) {
  unsigned u = __float_as_uint(f);
  unsigned r = u + 0x7fffu + ((u >> 16) & 1u);   // RNE to bf16
  return (short)(r >> 16);
}

// ---------------------------------------------------------------------------
// K0a: partial pairwise sums for sq = np.sum(xt*xt, -1).  Each thread computes
// one 128-block's tree value bs[blk] (bit-identical to the verified r4 tree:
// 8 SIMD regs of 16 lanes, ((r0+r1)+(r2+r3))+((r4+r5)+(r6+r7)), lane-halving).
// 16x more parallel than r4's monolithic kernel (was ~8 blocks, latency-bound).
// ---------------------------------------------------------------------------
__global__ __launch_bounds__(256) void k_sqnp_part(const float* __restrict__ x,
                                                   float* __restrict__ part) {
  const int t = blockIdx.x * 256 + threadIdx.x;
  if (t >= B_ * E_ * 16) return;
  const int be = t & (B_ * E_ - 1), blk = t >> 11;   // be fastest -> coalesced
  const int b = be >> 9, e = be & (E_ - 1);
  const float* p = x + (size_t)b * N_ * E_ + (size_t)blk * 128 * E_ + e;
  float lane[16];
#pragma unroll
  for (int l = 0; l < 16; l++) {
    float pr[8];
#pragma unroll
    for (int j = 0; j < 8; j++) {
      float v = p[(size_t)(j * 16 + l) * E_];
      pr[j] = __fmul_rn(v, v);
    }
    float s01 = __fadd_rn(pr[0], pr[1]);
    float s23 = __fadd_rn(pr[2], pr[3]);
    float s45 = __fadd_rn(pr[4], pr[5]);
    float s67 = __fadd_rn(pr[6], pr[7]);
    lane[l] = __fadd_rn(__fadd_rn(s01, s23), __fadd_rn(s45, s67));
  }
  float bb[8];
#pragma unroll
  for (int l = 0; l < 8; l++) bb[l] = __fadd_rn(lane[l], lane[l + 8]);
  float cc[4];
#pragma unroll
  for (int l = 0; l < 4; l++) cc[l] = __fadd_rn(bb[l], bb[l + 4]);
  part[(size_t)be * 16 + blk] =
      __fadd_rn(__fadd_rn(cc[0], cc[1]), __fadd_rn(cc[2], cc[3]));
}

// K0b: exact final tree over the 16 block values (matches r4 combine order).
__global__ __launch_bounds__(256) void k_sqnp_fin(const float* __restrict__ part,
                                                  float* __restrict__ sq) {
  const int t = blockIdx.x * 256 + threadIdx.x;
  if (t >= B_ * E_) return;
  const float* bs = part + (size_t)t * 16;
  float t1[8], t2[4];
#pragma unroll
  for (int l = 0; l < 8; l++) t1[l] = __fadd_rn(bs[2 * l], bs[2 * l + 1]);
#pragma unroll
  for (int l = 0; l < 4; l++) t2[l] = __fadd_rn(t1[2 * l], t1[2 * l + 1]);
  sq[t] = __fadd_rn(__fadd_rn(t2[0], t2[1]), __fadd_rn(t2[2], t2[3]));
}

// ---------------------------------------------------------------------------
// K1: Gram via numpy-exact sequential no-FMA chain, SYMMETRIC tiles only.
// G[i][j] == G[j][i] bitwise (fmul commutes bitwise; identical fadd chain in
// ascending n), so only upper-triangle 32x32 tile pairs are computed and
// mirrored. n-major LDS [nn][36]: float4 staging writes hit banks 0..31 once
// per 8-lane phase (conflict-free); b64 pair-reads cover 32 banks. Register
// prefetch of the next chunk hides HBM under the 8-VALU/nn compute.
// ---------------------------------------------------------------------------
__global__ __launch_bounds__(256) void k_gram_sym(const float* __restrict__ x,
                                                  float* __restrict__ g) {
  __shared__ float xs[32][36];
  __shared__ float ys[32][36];
  int p = blockIdx.x;                    // 0..135 upper-tri pair index
  const int b = blockIdx.y;
  int ti = 0;
  while (p >= 16 - ti) { p -= 16 - ti; ti++; }
  const int tj = ti + p;
  const int i0 = ti * 32, j0 = tj * 32;
  const int tid = threadIdx.x;
  const int li = tid & 15, lj = tid >> 4;
  const int snn = tid >> 3, sc4 = (tid & 7) * 4;
  const float* xb = x + (size_t)b * N_ * E_;

  float a00 = 0.f, a01 = 0.f, a10 = 0.f, a11 = 0.f;
  float4 px = *(const float4*)(xb + (size_t)snn * E_ + i0 + sc4);
  float4 py = *(const float4*)(xb + (size_t)snn * E_ + j0 + sc4);

  for (int n0 = 0; n0 < N_; n0 += 32) {
    __syncthreads();                     // prev chunk's reads done
    *(float4*)&xs[snn][sc4] = px;
    *(float4*)&ys[snn][sc4] = py;
    __syncthreads();
    if (n0 + 32 < N_) {
      px = *(const float4*)(xb + (size_t)(n0 + 32 + snn) * E_ + i0 + sc4);
      py = *(const float4*)(xb + (size_t)(n0 + 32 + snn) * E_ + j0 + sc4);
    }
#pragma unroll
    for (int nn = 0; nn < 32; nn++) {
      const float2 va = *(const float2*)&xs[nn][li * 2];
      const float2 vb = *(const float2*)&ys[nn][lj * 2];
      a00 = __fadd_rn(a00, __fmul_rn(va.x, vb.x));
      a01 = __fadd_rn(a01, __fmul_rn(va.x, vb.y));
      a10 = __fadd_rn(a10, __fmul_rn(va.y, vb.x));
      a11 = __fadd_rn(a11, __fmul_rn(va.y, vb.y));
    }
  }
  float* gb = g + (size_t)b * E_ * E_;
  const int i = i0 + li * 2, j = j0 + lj * 2;
  gb[(size_t)i * E_ + j]           = a00;
  gb[(size_t)i * E_ + j + 1]       = a01;
  gb[(size_t)(i + 1) * E_ + j]     = a10;
  gb[(size_t)(i + 1) * E_ + j + 1] = a11;
  if (ti != tj) {                        // mirror (bitwise-identical values)
    gb[(size_t)j * E_ + i]           = a00;
    gb[(size_t)(j + 1) * E_ + i]     = a01;
    gb[(size_t)j * E_ + i + 1]       = a10;
    gb[(size_t)(j + 1) * E_ + i + 1] = a11;
  }
}

// ---------------------------------------------------------------------------
// K2: top-16 smallest dist, fp32 formula, ties -> lower index (verified r4).
// ---------------------------------------------------------------------------
__global__ __launch_bounds__(256) void k_topk(const float* __restrict__ sq,
                                              const float* __restrict__ g,
                                              int* __restrict__ idxout) {
  const int bi = blockIdx.x;            // b*E + i
  const int b = bi >> 9, i = bi & (E_ - 1);
  const int tid = threadIdx.x;
  const float* gb = g + ((size_t)b * E_ + i) * E_;
  const float* sqb = sq + ((size_t)b << 9);
  __shared__ float val[E_];
  __shared__ float rv[256];
  __shared__ int ri[256];
  const float sqi = sqb[i];
  for (int j = tid; j < E_; j += 256) {
    val[j] = __fsub_rn(__fadd_rn(sqi, sqb[j]), __fmul_rn(2.0f, gb[j]));
  }
  __syncthreads();
  for (int t = 0; t < KNN_; t++) {
    float best = 3.0e38f; int bidx = E_;
    for (int j = tid; j < E_; j += 256) {
      float v = val[j];
      if (v < best) { best = v; bidx = j; }
    }
    rv[tid] = best; ri[tid] = bidx;
    __syncthreads();
    for (int s = 128; s > 0; s >>= 1) {
      if (tid < s) {
        float v2 = rv[tid + s]; int i2 = ri[tid + s];
        if (v2 < rv[tid] || (v2 == rv[tid] && i2 < ri[tid])) {
          rv[tid] = v2; ri[tid] = i2;
        }
      }
      __syncthreads();
    }
    if (tid == 0) {
      idxout[(size_t)bi * KNN_ + t] = ri[0];
      val[ri[0]] = 3.0e38f;
    }
    __syncthreads();
  }
}

// ---------------------------------------------------------------------------
// K3: x_knn mean + interleaved q into output's q half (verified r4).
// ---------------------------------------------------------------------------
__global__ __launch_bounds__(256) void k_knnmean(const float* __restrict__ x,
                                                 const int* __restrict__ idx,
                                                 float* __restrict__ out) {
  const int n = blockIdx.x, b = blockIdx.y;
  const int tid = threadIdx.x;
  __shared__ float xrow[E_];
  const float* xr = x + ((size_t)b * N_ + n) * E_;
  for (int i = tid; i < E_; i += 256) xrow[i] = xr[i];
  __syncthreads();
  float* orow = out + ((size_t)b * (2 * N_) + n) * EMB_;
  for (int i = tid; i < E_; i += 256) {
    const int* id = idx + ((size_t)b * E_ + i) * KNN_;
    float s = 0.f;
#pragma unroll
    for (int t = 0; t < KNN_; t++) s = __fadd_rn(s, xrow[id[t]]);
    float2 w; w.x = xrow[i]; w.y = s * (1.0f / 16.0f);
    *(float2*)&orow[2 * i] = w;
  }
}

// ---------------------------------------------------------------------------
// cvt: fp32 -> bf16, 8 elems/thread, contiguous.
// ---------------------------------------------------------------------------
__global__ __launch_bounds__(256) void k_cvt(const float* __restrict__ src,
                                             short* __restrict__ dst, int n8) {
  const int t = blockIdx.x * 256 + threadIdx.x;
  if (t >= n8) return;
  const float* s = src + (size_t)t * 8;
  float4 a = *(const float4*)s, b = *(const float4*)(s + 4);
  short8_t v;
  v[0] = f2bf(a.x); v[1] = f2bf(a.y); v[2] = f2bf(a.z); v[3] = f2bf(a.w);
  v[4] = f2bf(b.x); v[5] = f2bf(b.y); v[6] = f2bf(b.z); v[7] = f2bf(b.w);
  *(short8_t*)(dst + (size_t)t * 8) = v;
}

// cvt of q (strided: rows live in out's q-half with batch stride 2N*EMB)
__global__ __launch_bounds__(256) void k_cvt_q(const float* __restrict__ outq,
                                               short* __restrict__ dst) {
  const int t = blockIdx.x * 256 + threadIdx.x;  // chunk of 8, 8192*128 total
  const int row = t >> 7, c = (t & 127) * 8;
  const int b = row >> 11, n = row & (N_ - 1);
  const float* s = outq + ((size_t)b * 2 * N_ + n) * EMB_ + c;
  float4 a = *(const float4*)s, bb = *(const float4*)(s + 4);
  short8_t v;
  v[0] = f2bf(a.x);  v[1] = f2bf(a.y);  v[2] = f2bf(a.z);  v[3] = f2bf(a.w);
  v[4] = f2bf(bb.x); v[5] = f2bf(bb.y); v[6] = f2bf(bb.z); v[7] = f2bf(bb.w);
  *(short8_t*)(dst + (size_t)row * EMB_ + c) = v;
}

// ---------------------------------------------------------------------------
// K4: bf16 MFMA projection GEMM (verified r6). 128x128 tile, BK=64, 4 waves,
// 4x4 16x16x32 frags. MODE 0: bf16 row-major; MODE 1: fp32 into out rows
// [N,2N); MODE 2: bf16 transposed [b][col][n] (V^T for flash).
// ---------------------------------------------------------------------------
template<int MODE>
__global__ __launch_bounds__(256) void k_gemm_bf16(
    const short* __restrict__ X, const short* __restrict__ W,
    const float* __restrict__ bias, short* __restrict__ Yb,
    float* __restrict__ Yf) {
  __shared__ __align__(16) short As[128 * 64];
  __shared__ __align__(16) short Bs[128 * 64];
  const int tid = threadIdx.x;
  const int row0 = blockIdx.x * 128, col0 = blockIdx.y * 128;
  const int l = tid & 63, lg = l >> 4, lq = l & 15;
  const int w = tid >> 6, wm = w >> 1, wn = w & 1;
  float4_t acc[4][4];
#pragma unroll
  for (int i = 0; i < 4; i++)
#pragma unroll
    for (int j = 0; j < 4; j++) {
      acc[i][j][0] = 0.f; acc[i][j][1] = 0.f; acc[i][j][2] = 0.f; acc[i][j][3] = 0.f;
    }

  int rr_[4], cc_[4];
#pragma unroll
  for (int ii = 0; ii < 4; ii++) {
    const int cid = ii * 256 + tid;
    rr_[ii] = cid >> 3; cc_[ii] = cid & 7;
  }
  short8_t ar[4], br[4];
#pragma unroll
  for (int ii = 0; ii < 4; ii++) {
    ar[ii] = *(const short8_t*)(X + (size_t)(row0 + rr_[ii]) * EMB_ + cc_[ii] * 8);
    br[ii] = *(const short8_t*)(W + (size_t)(col0 + rr_[ii]) * EMB_ + cc_[ii] * 8);
  }

  for (int kt = 0; kt < 16; kt++) {
    __syncthreads();
#pragma unroll
    for (int ii = 0; ii < 4; ii++) {
      const int idx = rr_[ii] * 64 + ((cc_[ii] * 8) ^ ((rr_[ii] & 7) << 3));
      *(short8_t*)&As[idx] = ar[ii];
      *(short8_t*)&Bs[idx] = br[ii];
    }
    __syncthreads();
    if (kt < 15) {
#pragma unroll
      for (int ii = 0; ii < 4; ii++) {
        ar[ii] = *(const short8_t*)(X + (size_t)(row0 + rr_[ii]) * EMB_ + (kt + 1) * 64 + cc_[ii] * 8);
        br[ii] = *(const short8_t*)(W + (size_t)(col0 + rr_[ii]) * EMB_ + (kt + 1) * 64 + cc_[ii] * 8);
      }
    }
#pragma unroll
    for (int kk = 0; kk < 2; kk++) {
      short8_t af[4], bf[4];
#pragma unroll
      for (int mi = 0; mi < 4; mi++) {
        const int r = wm * 64 + mi * 16 + lq;
        af[mi] = *(const short8_t*)&As[r * 64 + ((kk * 32 + lg * 8) ^ ((r & 7) << 3))];
      }
#pragma unroll
      for (int ni = 0; ni < 4; ni++) {
        const int r = wn * 64 + ni * 16 + lq;
        bf[ni] = *(const short8_t*)&Bs[r * 64 + ((kk * 32 + lg * 8) ^ ((r & 7) << 3))];
      }
#pragma unroll
      for (int mi = 0; mi < 4; mi++)
#pragma unroll
        for (int ni = 0; ni < 4; ni++)
          acc[mi][ni] = __builtin_amdgcn_mfma_f32_16x16x32_bf16(af[mi], bf[ni], acc[mi][ni], 0, 0, 0);
    }
  }
#pragma unroll
  for (int ni = 0; ni < 4; ni++) {
    const int col = col0 + wn * 64 + ni * 16 + lq;
    const float bv = bias[col];
#pragma unroll
    for (int mi = 0; mi < 4; mi++) {
#pragma unroll
      for (int j = 0; j < 4; j++) {
        const int m = row0 + wm * 64 + mi * 16 + lg * 4 + j;
        const float v = acc[mi][ni][j] + bv;
        if (MODE == 0) {
          Yb[(size_t)m * EMB_ + col] = f2bf(v);
        } else if (MODE == 1) {
          const int b2 = m >> 11, n2 = m & (N_ - 1);
          Yf[((size_t)b2 * 2 * N_ + N_ + n2) * EMB_ + col] = v;
        } else {
          const int b2 = m >> 11, n2 = m & (N_ - 1);
          Yb[((size_t)b2 * EMB_ + col) * N_ + n2] = f2bf(v);
        }
      }
    }
  }
}

// ---------------------------------------------------------------------------
// K5: bf16 flash attention (verified r6). V passed as V^T [b][col][n].
// ---------------------------------------------------------------------------
__global__ __launch_bounds__(256) void k_flash_bf16(
    const short* __restrict__ Qg, const short* __restrict__ Kg,
    const short* __restrict__ Vtg, short* __restrict__ Og) {
  __shared__ __align__(16) short Ks[64 * 128];
  __shared__ __align__(16) short Vs[128 * 64];
  __shared__ __align__(16) short Ps[4][16 * 64];
  const int tid = threadIdx.x;
  const int w = tid >> 6, l = tid & 63, lg = l >> 4, lq = l & 15;
  const int bid = blockIdx.x;
  const int bh = (bid & 7) * 4 + ((bid >> 3) >> 5);
  const int rt = (bid >> 3) & 31;
  const int b = bh >> 3, h = bh & 7;
  const float scale = 0.08838834764831845f;
  const size_t bhoff = (size_t)b * N_ * EMB_ + (size_t)h * D_;
  const int qsw = (lq & 7) << 3;

  short8_t qf[4];
  {
    const short* qrow = Qg + bhoff + (size_t)(rt * 64 + w * 16 + lq) * EMB_;
#pragma unroll
    for (int kk = 0; kk < 4; kk++)
      qf[kk] = *(const short8_t*)(qrow + kk * 32 + lg * 8);
  }
  float4_t oacc[8];
#pragma unroll
  for (int mc = 0; mc < 8; mc++) {
    oacc[mc][0] = 0.f; oacc[mc][1] = 0.f; oacc[mc][2] = 0.f; oacc[mc][3] = 0.f;
  }
  float m = -3.0e38f, lsum = 0.f;

  const short* Vbase = Vtg + (size_t)b * EMB_ * N_ + (size_t)(h * D_) * N_;

  for (int kt = 0; kt < N_ / 64; kt++) {
    __syncthreads();
    const short* Kt = Kg + bhoff + (size_t)(kt * 64) * EMB_;
    const short* Vt = Vbase + kt * 64;
#pragma unroll
    for (int ii = 0; ii < 4; ii++) {
      const int cid = ii * 256 + tid;
      {
        const int r = cid >> 4, c = cid & 15;
        *(short8_t*)&Ks[r * 128 + ((c * 8) ^ ((r & 7) << 3))] =
            *(const short8_t*)(Kt + (size_t)r * EMB_ + c * 8);
      }
      {
        const int r = cid >> 3, c = cid & 7;
        *(short8_t*)&Vs[r * 64 + ((c * 8) ^ ((r & 7) << 3))] =
            *(const short8_t*)(Vt + (size_t)r * N_ + c * 8);
      }
    }
    __syncthreads();

    float4_t sc[4];
#pragma unroll
    for (int c = 0; c < 4; c++) {
      sc[c][0] = 0.f; sc[c][1] = 0.f; sc[c][2] = 0.f; sc[c][3] = 0.f;
      const int krow = c * 16 + lq;
#pragma unroll
      for (int kk = 0; kk < 4; kk++) {
        short8_t kf = *(const short8_t*)&Ks[krow * 128 + ((kk * 32 + lg * 8) ^ qsw)];
        sc[c] = __builtin_amdgcn_mfma_f32_16x16x32_bf16(kf, qf[kk], sc[c], 0, 0, 0);
      }
    }

    float tm = -3.0e38f;
#pragma unroll
    for (int c = 0; c < 4; c++)
#pragma unroll
      for (int j = 0; j < 4; j++) { sc[c][j] *= scale; tm = fmaxf(tm, sc[c][j]); }
    tm = fmaxf(tm, __shfl_xor(tm, 16));
    tm = fmaxf(tm, __shfl_xor(tm, 32));
    const float mn = fmaxf(m, tm);
    const float alpha = __expf(m - mn);
    m = mn;
    float ps = 0.f;
    short4_t pb[4];
#pragma unroll
    for (int c = 0; c < 4; c++) {
#pragma unroll
      for (int j = 0; j < 4; j++) {
        float p = __expf(sc[c][j] - mn);
        ps += p;
        pb[c][j] = f2bf(p);
      }
    }
    ps += __shfl_xor(ps, 16);
    ps += __shfl_xor(ps, 32);
    lsum = lsum * alpha + ps;

#pragma unroll
    for (int c = 0; c < 4; c++)
      *(short4_t*)&Ps[w][lq * 64 + ((c * 16 + lg * 4) ^ qsw)] = pb[c];

#pragma unroll
    for (int mc = 0; mc < 8; mc++) {
      oacc[mc][0] *= alpha; oacc[mc][1] *= alpha;
      oacc[mc][2] *= alpha; oacc[mc][3] *= alpha;
    }
#pragma unroll
    for (int kk = 0; kk < 2; kk++) {
      short8_t pf = *(const short8_t*)&Ps[w][lq * 64 + ((kk * 32 + lg * 8) ^ qsw)];
#pragma unroll
      for (int mc = 0; mc < 8; mc++) {
        const int dd = mc * 16 + lq;
        short8_t vf = *(const short8_t*)&Vs[dd * 64 + ((kk * 32 + lg * 8) ^ qsw)];
        oacc[mc] = __builtin_amdgcn_mfma_f32_16x16x32_bf16(vf, pf, oacc[mc], 0, 0, 0);
      }
    }
  }

  const float linv = 1.0f / lsum;
  short* orow = Og + bhoff + (size_t)(rt * 64 + w * 16 + lq) * EMB_;
#pragma unroll
  for (int mc = 0; mc < 8; mc++) {
    short4_t o;
    o[0] = f2bf(oacc[mc][0] * linv); o[1] = f2bf(oacc[mc][1] * linv);
    o[2] = f2bf(oacc[mc][2] * linv); o[3] = f2bf(oacc[mc][3] * linv);
    *(short4_t*)&orow[mc * 16 + lg * 4] = o;
  }
}

// ---------------------------------------------------------------------------
extern "C" void kernel_launch(void* const* d_in, const int* in_sizes, int n_in,
                              void* d_out, int out_size, void* d_ws, size_t ws_size,
                              hipStream_t stream) {
  const float* x     = (const float*)d_in[0];
  const float* x_enc = (const float*)d_in[1];
  const float* w_in  = (const float*)d_in[2];
  const float* b_in  = (const float*)d_in[3];
  const float* w_out = (const float*)d_in[4];
  const float* b_out = (const float*)d_in[5];
  float* out = (float*)d_out;
  char* wsb = (char*)d_ws;

  const size_t oG    = 0;
  const size_t oSq   = oG + (size_t)B_ * E_ * E_ * 4;
  const size_t oPart = oSq + (size_t)B_ * E_ * 4;
  const size_t oIdx  = oPart + (size_t)B_ * E_ * 16 * 4;
  const size_t oXq   = (oIdx + (size_t)B_ * E_ * KNN_ * 4 + 255) & ~(size_t)255;
  const size_t sB    = (size_t)B_ * N_ * EMB_ * 2;     // 16 MB bf16 buffer
  const size_t oXe   = oXq + sB;
  const size_t oWin  = oXe + sB;
  const size_t oWo   = oWin + 3ull * EMB_ * EMB_ * 2;
  const size_t oQ    = oWo + (size_t)EMB_ * EMB_ * 2;
  const size_t oK    = oQ + sB;
  const size_t oV    = oK + sB;
  const size_t oO    = oV + sB;
  const size_t need  = oO + sB;

  float* g    = (float*)(wsb + oG);
  float* sqv  = (float*)(wsb + oSq);
  float* part = (float*)(wsb + oPart);
  int*   idx  = (int*)(wsb + oIdx);
  short* Xq   = (short*)(wsb + oXq);
  short* Xe   = (short*)(wsb + oXe);
  short* Win  = (short*)(wsb + oWin);
  short* Wo   = (short*)(wsb + oWo);
  short* Qb   = (short*)(wsb + oQ);
  short* Kb   = (short*)(wsb + oK);
  short* Vb   = (short*)(wsb + oV);
  short* Ob   = (ws_size >= need) ? (short*)(wsb + oO) : Qb;

  // 1) kNN emulating the numpy reference's fp32 numerics exactly
  k_sqnp_part<<<dim3(B_ * E_ * 16 / 256), 256, 0, stream>>>(x, part);
  k_sqnp_fin<<<dim3(B_ * E_ / 256), 256, 0, stream>>>(part, sqv);
  k_gram_sym<<<dim3(136, B_), 256, 0, stream>>>(x, g);
  k_topk<<<dim3(B_ * E_), 256, 0, stream>>>(sqv, g, idx);
  k_knnmean<<<dim3(N_, B_), 256, 0, stream>>>(x, idx, out);

  // 2) bf16 conversions
  k_cvt<<<dim3(4096), 256, 0, stream>>>(x_enc, Xe, B_ * N_ * EMB_ / 8);
  k_cvt<<<dim3(1536), 256, 0, stream>>>(w_in, Win, 3 * EMB_ * EMB_ / 8);
  k_cvt<<<dim3(512), 256, 0, stream>>>(w_out, Wo, EMB_ * EMB_ / 8);
  k_cvt_q<<<dim3(4096), 256, 0, stream>>>(out, Xq);

  // 3) projections (bf16 MFMA); V written transposed for flash
  k_gemm_bf16<0><<<dim3(64, 8), 256, 0, stream>>>(Xq, Win, b_in, Qb, nullptr);
  k_gemm_bf16<0><<<dim3(64, 8), 256, 0, stream>>>(Xe, Win + (size_t)EMB_ * EMB_,
                                                  b_in + EMB_, Kb, nullptr);
  k_gemm_bf16<2><<<dim3(64, 8), 256, 0, stream>>>(Xe, Win + 2ull * EMB_ * EMB_,
                                                  b_in + 2 * EMB_, Vb, nullptr);

  // 4) attention (bf16 MFMA flash, V^T input)
  k_flash_bf16<<<dim3(1024), 256, 0, stream>>>(Qb, Kb, Vb, Ob);

  // 5) output projection -> fp32 into out rows [N, 2N)
  k_gemm_bf16<1><<<dim3(64, 8), 256, 0, stream>>>(Ob, Wo, b_out, nullptr, out);
}

// Round 9
// 395.311 us; speedup vs baseline: 6.7004x; 1.0047x over previous
//
#include <hip/hip_runtime.h>
#include <hip/hip_bf16.h>

#define B_ 4
#define N_ 2048
#define E_ 512
#define EMB_ 1024
#define H_ 8
#define D_ 128
#define KNN_ 16

typedef short short8_t __attribute__((ext_vector_type(8)));
typedef short short4_t __attribute__((ext_vector_type(4)));
typedef float float4_t __attribute__((ext_vector_type(4)));

__device__ __forceinline__ short f2bf(float f) {
  unsigned u = __float_as_uint(f);
  unsigned r = u + 0x7fffu + ((u >> 16) & 1u);   // RNE to bf16
  return (short)(r >> 16);
}

// pack 2 floats -> 2 bf16 in one u32 (x -> low 16, y -> high 16)
__device__ __forceinline__ unsigned pk2bf(float a, float b) {
  float2 f; f.x = a; f.y = b;
  __hip_bfloat162 h = __float22bfloat162_rn(f);
  return *(unsigned*)&h;
}

// fast 2^x (v_exp_f32)
__device__ __forceinline__ float fexp2(float x) {
  return __builtin_amdgcn_exp2f(x);
}

// ---------------------------------------------------------------------------
// K0a: partial pairwise sums for sq = np.sum(xt*xt, -1) (verified r7).
// ---------------------------------------------------------------------------
__global__ __launch_bounds__(256) void k_sqnp_part(const float* __restrict__ x,
                                                   float* __restrict__ part) {
  const int t = blockIdx.x * 256 + threadIdx.x;
  if (t >= B_ * E_ * 16) return;
  const int be = t & (B_ * E_ - 1), blk = t >> 11;
  const int b = be >> 9, e = be & (E_ - 1);
  const float* p = x + (size_t)b * N_ * E_ + (size_t)blk * 128 * E_ + e;
  float lane[16];
#pragma unroll
  for (int l = 0; l < 16; l++) {
    float pr[8];
#pragma unroll
    for (int j = 0; j < 8; j++) {
      float v = p[(size_t)(j * 16 + l) * E_];
      pr[j] = __fmul_rn(v, v);
    }
    float s01 = __fadd_rn(pr[0], pr[1]);
    float s23 = __fadd_rn(pr[2], pr[3]);
    float s45 = __fadd_rn(pr[4], pr[5]);
    float s67 = __fadd_rn(pr[6], pr[7]);
    lane[l] = __fadd_rn(__fadd_rn(s01, s23), __fadd_rn(s45, s67));
  }
  float bb[8];
#pragma unroll
  for (int l = 0; l < 8; l++) bb[l] = __fadd_rn(lane[l], lane[l + 8]);
  float cc[4];
#pragma unroll
  for (int l = 0; l < 4; l++) cc[l] = __fadd_rn(bb[l], bb[l + 4]);
  part[(size_t)be * 16 + blk] =
      __fadd_rn(__fadd_rn(cc[0], cc[1]), __fadd_rn(cc[2], cc[3]));
}

// K0b: exact final tree over the 16 block values (verified r7).
__global__ __launch_bounds__(256) void k_sqnp_fin(const float* __restrict__ part,
                                                  float* __restrict__ sq) {
  const int t = blockIdx.x * 256 + threadIdx.x;
  if (t >= B_ * E_) return;
  const float* bs = part + (size_t)t * 16;
  float t1[8], t2[4];
#pragma unroll
  for (int l = 0; l < 8; l++) t1[l] = __fadd_rn(bs[2 * l], bs[2 * l + 1]);
#pragma unroll
  for (int l = 0; l < 4; l++) t2[l] = __fadd_rn(t1[2 * l], t1[2 * l + 1]);
  sq[t] = __fadd_rn(__fadd_rn(t2[0], t2[1]), __fadd_rn(t2[2], t2[3]));
}

// ---------------------------------------------------------------------------
// K1: Gram, numpy-exact sequential no-FMA chain, symmetric tiles (verified r7).
// ---------------------------------------------------------------------------
__global__ __launch_bounds__(256) void k_gram_sym(const float* __restrict__ x,
                                                  float* __restrict__ g) {
  __shared__ float xs[32][36];
  __shared__ float ys[32][36];
  int p = blockIdx.x;                    // 0..135 upper-tri pair index
  const int b = blockIdx.y;
  int ti = 0;
  while (p >= 16 - ti) { p -= 16 - ti; ti++; }
  const int tj = ti + p;
  const int i0 = ti * 32, j0 = tj * 32;
  const int tid = threadIdx.x;
  const int li = tid & 15, lj = tid >> 4;
  const int snn = tid >> 3, sc4 = (tid & 7) * 4;
  const float* xb = x + (size_t)b * N_ * E_;

  float a00 = 0.f, a01 = 0.f, a10 = 0.f, a11 = 0.f;
  float4 px = *(const float4*)(xb + (size_t)snn * E_ + i0 + sc4);
  float4 py = *(const float4*)(xb + (size_t)snn * E_ + j0 + sc4);

  for (int n0 = 0; n0 < N_; n0 += 32) {
    __syncthreads();
    *(float4*)&xs[snn][sc4] = px;
    *(float4*)&ys[snn][sc4] = py;
    __syncthreads();
    if (n0 + 32 < N_) {
      px = *(const float4*)(xb + (size_t)(n0 + 32 + snn) * E_ + i0 + sc4);
      py = *(const float4*)(xb + (size_t)(n0 + 32 + snn) * E_ + j0 + sc4);
    }
#pragma unroll
    for (int nn = 0; nn < 32; nn++) {
      const float2 va = *(const float2*)&xs[nn][li * 2];
      const float2 vb = *(const float2*)&ys[nn][lj * 2];
      a00 = __fadd_rn(a00, __fmul_rn(va.x, vb.x));
      a01 = __fadd_rn(a01, __fmul_rn(va.x, vb.y));
      a10 = __fadd_rn(a10, __fmul_rn(va.y, vb.x));
      a11 = __fadd_rn(a11, __fmul_rn(va.y, vb.y));
    }
  }
  float* gb = g + (size_t)b * E_ * E_;
  const int i = i0 + li * 2, j = j0 + lj * 2;
  gb[(size_t)i * E_ + j]           = a00;
  gb[(size_t)i * E_ + j + 1]       = a01;
  gb[(size_t)(i + 1) * E_ + j]     = a10;
  gb[(size_t)(i + 1) * E_ + j + 1] = a11;
  if (ti != tj) {
    gb[(size_t)j * E_ + i]           = a00;
    gb[(size_t)(j + 1) * E_ + i]     = a01;
    gb[(size_t)j * E_ + i + 1]       = a10;
    gb[(size_t)(j + 1) * E_ + i + 1] = a11;
  }
}

// ---------------------------------------------------------------------------
// K2: top-16 smallest dist, fp32 formula, ties -> lower index (verified r4).
// ---------------------------------------------------------------------------
__global__ __launch_bounds__(256) void k_topk(const float* __restrict__ sq,
                                              const float* __restrict__ g,
                                              int* __restrict__ idxout) {
  const int bi = blockIdx.x;            // b*E + i
  const int b = bi >> 9, i = bi & (E_ - 1);
  const int tid = threadIdx.x;
  const float* gb = g + ((size_t)b * E_ + i) * E_;
  const float* sqb = sq + ((size_t)b << 9);
  __shared__ float val[E_];
  __shared__ float rv[256];
  __shared__ int ri[256];
  const float sqi = sqb[i];
  for (int j = tid; j < E_; j += 256) {
    val[j] = __fsub_rn(__fadd_rn(sqi, sqb[j]), __fmul_rn(2.0f, gb[j]));
  }
  __syncthreads();
  for (int t = 0; t < KNN_; t++) {
    float best = 3.0e38f; int bidx = E_;
    for (int j = tid; j < E_; j += 256) {
      float v = val[j];
      if (v < best) { best = v; bidx = j; }
    }
    rv[tid] = best; ri[tid] = bidx;
    __syncthreads();
    for (int s = 128; s > 0; s >>= 1) {
      if (tid < s) {
        float v2 = rv[tid + s]; int i2 = ri[tid + s];
        if (v2 < rv[tid] || (v2 == rv[tid] && i2 < ri[tid])) {
          rv[tid] = v2; ri[tid] = i2;
        }
      }
      __syncthreads();
    }
    if (tid == 0) {
      idxout[(size_t)bi * KNN_ + t] = ri[0];
      val[ri[0]] = 3.0e38f;
    }
    __syncthreads();
  }
}

// ---------------------------------------------------------------------------
// K3: x_knn mean + interleaved q into output's q half (verified r4).
// ---------------------------------------------------------------------------
__global__ __launch_bounds__(256) void k_knnmean(const float* __restrict__ x,
                                                 const int* __restrict__ idx,
                                                 float* __restrict__ out) {
  const int n = blockIdx.x, b = blockIdx.y;
  const int tid = threadIdx.x;
  __shared__ float xrow[E_];
  const float* xr = x + ((size_t)b * N_ + n) * E_;
  for (int i = tid; i < E_; i += 256) xrow[i] = xr[i];
  __syncthreads();
  float* orow = out + ((size_t)b * (2 * N_) + n) * EMB_;
  for (int i = tid; i < E_; i += 256) {
    const int* id = idx + ((size_t)b * E_ + i) * KNN_;
    float s = 0.f;
#pragma unroll
    for (int t = 0; t < KNN_; t++) s = __fadd_rn(s, xrow[id[t]]);
    float2 w; w.x = xrow[i]; w.y = s * (1.0f / 16.0f);
    *(float2*)&orow[2 * i] = w;
  }
}

// ---------------------------------------------------------------------------
// cvt: fp32 -> bf16, 8 elems/thread, contiguous.
// ---------------------------------------------------------------------------
__global__ __launch_bounds__(256) void k_cvt(const float* __restrict__ src,
                                             short* __restrict__ dst, int n8) {
  const int t = blockIdx.x * 256 + threadIdx.x;
  if (t >= n8) return;
  const float* s = src + (size_t)t * 8;
  float4 a = *(const float4*)s, b = *(const float4*)(s + 4);
  short8_t v;
  v[0] = f2bf(a.x); v[1] = f2bf(a.y); v[2] = f2bf(a.z); v[3] = f2bf(a.w);
  v[4] = f2bf(b.x); v[5] = f2bf(b.y); v[6] = f2bf(b.z); v[7] = f2bf(b.w);
  *(short8_t*)(dst + (size_t)t * 8) = v;
}

// cvt of q (strided: rows live in out's q-half with batch stride 2N*EMB)
__global__ __launch_bounds__(256) void k_cvt_q(const float* __restrict__ outq,
                                               short* __restrict__ dst) {
  const int t = blockIdx.x * 256 + threadIdx.x;
  const int row = t >> 7, c = (t & 127) * 8;
  const int b = row >> 11, n = row & (N_ - 1);
  const float* s = outq + ((size_t)b * 2 * N_ + n) * EMB_ + c;
  float4 a = *(const float4*)s, bb = *(const float4*)(s + 4);
  short8_t v;
  v[0] = f2bf(a.x);  v[1] = f2bf(a.y);  v[2] = f2bf(a.z);  v[3] = f2bf(a.w);
  v[4] = f2bf(bb.x); v[5] = f2bf(bb.y); v[6] = f2bf(bb.z); v[7] = f2bf(bb.w);
  *(short8_t*)(dst + (size_t)row * EMB_ + c) = v;
}

// ---------------------------------------------------------------------------
// K4: bf16 MFMA projection GEMM (verified r6/r7).
// ---------------------------------------------------------------------------
template<int MODE>
__global__ __launch_bounds__(256) void k_gemm_bf16(
    const short* __restrict__ X, const short* __restrict__ W,
    const float* __restrict__ bias, short* __restrict__ Yb,
    float* __restrict__ Yf) {
  __shared__ __align__(16) short As[128 * 64];
  __shared__ __align__(16) short Bs[128 * 64];
  const int tid = threadIdx.x;
  const int row0 = blockIdx.x * 128, col0 = blockIdx.y * 128;
  const int l = tid & 63, lg = l >> 4, lq = l & 15;
  const int w = tid >> 6, wm = w >> 1, wn = w & 1;
  float4_t acc[4][4];
#pragma unroll
  for (int i = 0; i < 4; i++)
#pragma unroll
    for (int j = 0; j < 4; j++) {
      acc[i][j][0] = 0.f; acc[i][j][1] = 0.f; acc[i][j][2] = 0.f; acc[i][j][3] = 0.f;
    }

  int rr_[4], cc_[4];
#pragma unroll
  for (int ii = 0; ii < 4; ii++) {
    const int cid = ii * 256 + tid;
    rr_[ii] = cid >> 3; cc_[ii] = cid & 7;
  }
  short8_t ar[4], br[4];
#pragma unroll
  for (int ii = 0; ii < 4; ii++) {
    ar[ii] = *(const short8_t*)(X + (size_t)(row0 + rr_[ii]) * EMB_ + cc_[ii] * 8);
    br[ii] = *(const short8_t*)(W + (size_t)(col0 + rr_[ii]) * EMB_ + cc_[ii] * 8);
  }

  for (int kt = 0; kt < 16; kt++) {
    __syncthreads();
#pragma unroll
    for (int ii = 0; ii < 4; ii++) {
      const int idx = rr_[ii] * 64 + ((cc_[ii] * 8) ^ ((rr_[ii] & 7) << 3));
      *(short8_t*)&As[idx] = ar[ii];
      *(short8_t*)&Bs[idx] = br[ii];
    }
    __syncthreads();
    if (kt < 15) {
#pragma unroll
      for (int ii = 0; ii < 4; ii++) {
        ar[ii] = *(const short8_t*)(X + (size_t)(row0 + rr_[ii]) * EMB_ + (kt + 1) * 64 + cc_[ii] * 8);
        br[ii] = *(const short8_t*)(W + (size_t)(col0 + rr_[ii]) * EMB_ + (kt + 1) * 64 + cc_[ii] * 8);
      }
    }
#pragma unroll
    for (int kk = 0; kk < 2; kk++) {
      short8_t af[4], bf[4];
#pragma unroll
      for (int mi = 0; mi < 4; mi++) {
        const int r = wm * 64 + mi * 16 + lq;
        af[mi] = *(const short8_t*)&As[r * 64 + ((kk * 32 + lg * 8) ^ ((r & 7) << 3))];
      }
#pragma unroll
      for (int ni = 0; ni < 4; ni++) {
        const int r = wn * 64 + ni * 16 + lq;
        bf[ni] = *(const short8_t*)&Bs[r * 64 + ((kk * 32 + lg * 8) ^ ((r & 7) << 3))];
      }
#pragma unroll
      for (int mi = 0; mi < 4; mi++)
#pragma unroll
        for (int ni = 0; ni < 4; ni++)
          acc[mi][ni] = __builtin_amdgcn_mfma_f32_16x16x32_bf16(af[mi], bf[ni], acc[mi][ni], 0, 0, 0);
    }
  }
#pragma unroll
  for (int ni = 0; ni < 4; ni++) {
    const int col = col0 + wn * 64 + ni * 16 + lq;
    const float bv = bias[col];
#pragma unroll
    for (int mi = 0; mi < 4; mi++) {
#pragma unroll
      for (int j = 0; j < 4; j++) {
        const int m = row0 + wm * 64 + mi * 16 + lg * 4 + j;
        const float v = acc[mi][ni][j] + bv;
        if (MODE == 0) {
          Yb[(size_t)m * EMB_ + col] = f2bf(v);
        } else if (MODE == 1) {
          const int b2 = m >> 11, n2 = m & (N_ - 1);
          Yf[((size_t)b2 * 2 * N_ + N_ + n2) * EMB_ + col] = v;
        } else {
          const int b2 = m >> 11, n2 = m & (N_ - 1);
          Yb[((size_t)b2 * EMB_ + col) * N_ + n2] = f2bf(v);
        }
      }
    }
  }
}

// ---------------------------------------------------------------------------
// K5: bf16 flash attention, r9: exp2-fold + defer-max (THR=62.7 raw =
// 2^8 headroom) + packed bf16 cvt + async-STAGE split (T14) + setprio (T5).
// V passed as V^T [b][col][n]. Swapped QK^T keeps softmax lane-local.
// ---------------------------------------------------------------------------
__global__ __launch_bounds__(256, 4) void k_flash_bf16(
    const short* __restrict__ Qg, const short* __restrict__ Kg,
    const short* __restrict__ Vtg, short* __restrict__ Og) {
  __shared__ __align__(16) short Ks[64 * 128];
  __shared__ __align__(16) short Vs[128 * 64];
  __shared__ __align__(16) short Ps[4][16 * 64];
  const int tid = threadIdx.x;
  const int w = tid >> 6, l = tid & 63, lg = l >> 4, lq = l & 15;
  const int bid = blockIdx.x;
  const int bh = (bid & 7) * 4 + ((bid >> 3) >> 5);
  const int rt = (bid >> 3) & 31;
  const int b = bh >> 3, h = bh & 7;
  const float c1 = 0.08838834764831845f * 1.4426950408889634f;  // scale*log2e
  const size_t bhoff = (size_t)b * N_ * EMB_ + (size_t)h * D_;
  const int qsw = (lq & 7) << 3;

  // staging geometry (const per thread)
  int koff[4], vofs[4], klds[4], vlds[4];
#pragma unroll
  for (int ii = 0; ii < 4; ii++) {
    const int cid = ii * 256 + tid;
    const int kr = cid >> 4, kc = cid & 15;
    const int vr = cid >> 3, vc = cid & 7;
    koff[ii] = kr * EMB_ + kc * 8;
    vofs[ii] = vr * N_ + vc * 8;
    klds[ii] = kr * 128 + ((kc * 8) ^ ((kr & 7) << 3));
    vlds[ii] = vr * 64 + ((vc * 8) ^ ((vr & 7) << 3));
  }
  const short* Kt0 = Kg + bhoff;
  const short* Vt0 = Vtg + (size_t)b * EMB_ * N_ + (size_t)(h * D_) * N_;

  short8_t qf[4];
  {
    const short* qrow = Qg + bhoff + (size_t)(rt * 64 + w * 16 + lq) * EMB_;
#pragma unroll
    for (int kk = 0; kk < 4; kk++)
      qf[kk] = *(const short8_t*)(qrow + kk * 32 + lg * 8);
  }
  float4_t oacc[8];
#pragma unroll
  for (int mc = 0; mc < 8; mc++) {
    oacc[mc][0] = 0.f; oacc[mc][1] = 0.f; oacc[mc][2] = 0.f; oacc[mc][3] = 0.f;
  }
  float m = -3.0e38f, lsum = 0.f;

  short8_t kreg[4], vreg[4];
#pragma unroll
  for (int ii = 0; ii < 4; ii++) {       // prologue: tile 0 -> regs
    kreg[ii] = *(const short8_t*)(Kt0 + koff[ii]);
    vreg[ii] = *(const short8_t*)(Vt0 + vofs[ii]);
  }
#pragma unroll
  for (int ii = 0; ii < 4; ii++) {       // regs -> LDS
    *(short8_t*)&Ks[klds[ii]] = kreg[ii];
    *(short8_t*)&Vs[vlds[ii]] = vreg[ii];
  }
  __syncthreads();

  for (int kt = 0; kt < N_ / 64; kt++) {
    if (kt + 1 < N_ / 64) {              // issue next tile's loads early (T14)
      const short* Kt = Kt0 + (size_t)((kt + 1) * 64) * EMB_;
      const short* Vt = Vt0 + (kt + 1) * 64;
#pragma unroll
      for (int ii = 0; ii < 4; ii++) {
        kreg[ii] = *(const short8_t*)(Kt + koff[ii]);
        vreg[ii] = *(const short8_t*)(Vt + vofs[ii]);
      }
    }

    // ---- S^T = K . Q^T : sc[c][j] = S[q=lq][key = c*16 + lg*4 + j] (raw)
    float4_t sc[4];
    __builtin_amdgcn_s_setprio(1);
#pragma unroll
    for (int c = 0; c < 4; c++) {
      sc[c][0] = 0.f; sc[c][1] = 0.f; sc[c][2] = 0.f; sc[c][3] = 0.f;
      const int krow = c * 16 + lq;
#pragma unroll
      for (int kk = 0; kk < 4; kk++) {
        short8_t kf = *(const short8_t*)&Ks[krow * 128 + ((kk * 32 + lg * 8) ^ qsw)];
        sc[c] = __builtin_amdgcn_mfma_f32_16x16x32_bf16(kf, qf[kk], sc[c], 0, 0, 0);
      }
    }
    __builtin_amdgcn_s_setprio(0);

    // ---- online softmax with defer-max; p = exp2(S*c1 - m*c1)
    float tm = sc[0][0];
#pragma unroll
    for (int c = 0; c < 4; c++) {
      tm = fmaxf(tm, fmaxf(fmaxf(sc[c][0], sc[c][1]), fmaxf(sc[c][2], sc[c][3])));
    }
    tm = fmaxf(tm, __shfl_xor(tm, 16));
    tm = fmaxf(tm, __shfl_xor(tm, 32));
    if (__any(tm > m + 62.7f)) {         // 62.7*c1 = 8 -> P <= 2^8
      const float mn = fmaxf(m, tm);
      const float alpha = fexp2((m - mn) * c1);
      m = mn;
      lsum *= alpha;
#pragma unroll
      for (int mc = 0; mc < 8; mc++) {
        oacc[mc][0] *= alpha; oacc[mc][1] *= alpha;
        oacc[mc][2] *= alpha; oacc[mc][3] *= alpha;
      }
    }
    const float mc1 = m * c1;
    float ps = 0.f;
#pragma unroll
    for (int c = 0; c < 4; c++) {
      float p0 = fexp2(__builtin_fmaf(sc[c][0], c1, -mc1));
      float p1 = fexp2(__builtin_fmaf(sc[c][1], c1, -mc1));
      float p2 = fexp2(__builtin_fmaf(sc[c][2], c1, -mc1));
      float p3 = fexp2(__builtin_fmaf(sc[c][3], c1, -mc1));
      ps += (p0 + p1) + (p2 + p3);
      uint2 pw; pw.x = pk2bf(p0, p1); pw.y = pk2bf(p2, p3);
      *(uint2*)&Ps[w][lq * 64 + ((c * 16 + lg * 4) ^ qsw)] = pw;
    }
    ps += __shfl_xor(ps, 16);
    ps += __shfl_xor(ps, 32);
    lsum += ps;

    // ---- O^T += V^T . P^T
    __builtin_amdgcn_s_setprio(1);
#pragma unroll
    for (int kk = 0; kk < 2; kk++) {
      short8_t pf = *(const short8_t*)&Ps[w][lq * 64 + ((kk * 32 + lg * 8) ^ qsw)];
#pragma unroll
      for (int mc = 0; mc < 8; mc++) {
        const int dd = mc * 16 + lq;
        short8_t vf = *(const short8_t*)&Vs[dd * 64 + ((kk * 32 + lg * 8) ^ qsw)];
        oacc[mc] = __builtin_amdgcn_mfma_f32_16x16x32_bf16(vf, pf, oacc[mc], 0, 0, 0);
      }
    }
    __builtin_amdgcn_s_setprio(0);

    __syncthreads();                     // all waves done reading Ks/Vs
    if (kt + 1 < N_ / 64) {
#pragma unroll
      for (int ii = 0; ii < 4; ii++) {   // write-late (waits vmcnt on regs)
        *(short8_t*)&Ks[klds[ii]] = kreg[ii];
        *(short8_t*)&Vs[vlds[ii]] = vreg[ii];
      }
      __syncthreads();                   // writes visible before next QK^T
    }
  }

  const float linv = 1.0f / lsum;
  short* orow = Og + bhoff + (size_t)(rt * 64 + w * 16 + lq) * EMB_;
#pragma unroll
  for (int mc = 0; mc < 8; mc++) {
    short4_t o;
    o[0] = f2bf(oacc[mc][0] * linv); o[1] = f2bf(oacc[mc][1] * linv);
    o[2] = f2bf(oacc[mc][2] * linv); o[3] = f2bf(oacc[mc][3] * linv);
    *(short4_t*)&orow[mc * 16 + lg * 4] = o;
  }
}

// ---------------------------------------------------------------------------
extern "C" void kernel_launch(void* const* d_in, const int* in_sizes, int n_in,
                              void* d_out, int out_size, void* d_ws, size_t ws_size,
                              hipStream_t stream) {
  const float* x     = (const float*)d_in[0];
  const float* x_enc = (const float*)d_in[1];
  const float* w_in  = (const float*)d_in[2];
  const float* b_in  = (const float*)d_in[3];
  const float* w_out = (const float*)d_in[4];
  const float* b_out = (const float*)d_in[5];
  float* out = (float*)d_out;
  char* wsb = (char*)d_ws;

  const size_t oG    = 0;
  const size_t oSq   = oG + (size_t)B_ * E_ * E_ * 4;
  const size_t oPart = oSq + (size_t)B_ * E_ * 4;
  const size_t oIdx  = oPart + (size_t)B_ * E_ * 16 * 4;
  const size_t oXq   = (oIdx + (size_t)B_ * E_ * KNN_ * 4 + 255) & ~(size_t)255;
  const size_t sB    = (size_t)B_ * N_ * EMB_ * 2;
  const size_t oXe   = oXq + sB;
  const size_t oWin  = oXe + sB;
  const size_t oWo   = oWin + 3ull * EMB_ * EMB_ * 2;
  const size_t oQ    = oWo + (size_t)EMB_ * EMB_ * 2;
  const size_t oK    = oQ + sB;
  const size_t oV    = oK + sB;
  const size_t oO    = oV + sB;
  const size_t need  = oO + sB;

  float* g    = (float*)(wsb + oG);
  float* sqv  = (float*)(wsb + oSq);
  float* part = (float*)(wsb + oPart);
  int*   idx  = (int*)(wsb + oIdx);
  short* Xq   = (short*)(wsb + oXq);
  short* Xe   = (short*)(wsb + oXe);
  short* Win  = (short*)(wsb + oWin);
  short* Wo   = (short*)(wsb + oWo);
  short* Qb   = (short*)(wsb + oQ);
  short* Kb   = (short*)(wsb + oK);
  short* Vb   = (short*)(wsb + oV);
  short* Ob   = (ws_size >= need) ? (short*)(wsb + oO) : Qb;

  // 1) kNN emulating the numpy reference's fp32 numerics exactly
  k_sqnp_part<<<dim3(B_ * E_ * 16 / 256), 256, 0, stream>>>(x, part);
  k_sqnp_fin<<<dim3(B_ * E_ / 256), 256, 0, stream>>>(part, sqv);
  k_gram_sym<<<dim3(136, B_), 256, 0, stream>>>(x, g);
  k_topk<<<dim3(B_ * E_), 256, 0, stream>>>(sqv, g, idx);
  k_knnmean<<<dim3(N_, B_), 256, 0, stream>>>(x, idx, out);

  // 2) bf16 conversions
  k_cvt<<<dim3(4096), 256, 0, stream>>>(x_enc, Xe, B_ * N_ * EMB_ / 8);
  k_cvt<<<dim3(1536), 256, 0, stream>>>(w_in, Win, 3 * EMB_ * EMB_ / 8);
  k_cvt<<<dim3(512), 256, 0, stream>>>(w_out, Wo, EMB_ * EMB_ / 8);
  k_cvt_q<<<dim3(4096), 256, 0, stream>>>(out, Xq);

  // 3) projections (bf16 MFMA); V written transposed for flash
  k_gemm_bf16<0><<<dim3(64, 8), 256, 0, stream>>>(Xq, Win, b_in, Qb, nullptr);
  k_gemm_bf16<0><<<dim3(64, 8), 256, 0, stream>>>(Xe, Win + (size_t)EMB_ * EMB_,
                                                  b_in + EMB_, Kb, nullptr);
  k_gemm_bf16<2><<<dim3(64, 8), 256, 0, stream>>>(Xe, Win + 2ull * EMB_ * EMB_,
                                                  b_in + 2 * EMB_, Vb, nullptr);

  // 4) attention (bf16 MFMA flash, V^T input)
  k_flash_bf16<<<dim3(1024), 256, 0, stream>>>(Qb, Kb, Vb, Ob);

  // 5) output projection -> fp32 into out rows [N, 2N)
  k_gemm_bf16<1><<<dim3(64, 8), 256, 0, stream>>>(Ob, Wo, b_out, nullptr, out);
}

// Round 10
// 354.755 us; speedup vs baseline: 7.4664x; 1.1143x over previous
//
#include <hip/hip_runtime.h>
#include <hip/hip_bf16.h>

#define B_ 4
#define N_ 2048
#define E_ 512
#define EMB_ 1024
#define H_ 8
#define D_ 128
#define KNN_ 16

typedef short short8_t __attribute__((ext_vector_type(8)));
typedef short short4_t __attribute__((ext_vector_type(4)));
typedef float float4_t __attribute__((ext_vector_type(4)));
typedef float float16_t __attribute__((ext_vector_type(16)));

__device__ __forceinline__ short f2bf(float f) {
  unsigned u = __float_as_uint(f);
  unsigned r = u + 0x7fffu + ((u >> 16) & 1u);   // RNE to bf16
  return (short)(r >> 16);
}

// pack 2 floats -> 2 bf16 in one u32 (x -> low 16, y -> high 16)
__device__ __forceinline__ unsigned pk2bf(float a, float b) {
  float2 f; f.x = a; f.y = b;
  __hip_bfloat162 h = __float22bfloat162_rn(f);
  return *(unsigned*)&h;
}

// fast 2^x (v_exp_f32)
__device__ __forceinline__ float fexp2(float x) {
  return __builtin_amdgcn_exp2f(x);
}

// ---------------------------------------------------------------------------
// K0a: partial pairwise sums for sq = np.sum(xt*xt, -1) (verified r7).
// ---------------------------------------------------------------------------
__global__ __launch_bounds__(256) void k_sqnp_part(const float* __restrict__ x,
                                                   float* __restrict__ part) {
  const int t = blockIdx.x * 256 + threadIdx.x;
  if (t >= B_ * E_ * 16) return;
  const int be = t & (B_ * E_ - 1), blk = t >> 11;
  const int b = be >> 9, e = be & (E_ - 1);
  const float* p = x + (size_t)b * N_ * E_ + (size_t)blk * 128 * E_ + e;
  float lane[16];
#pragma unroll
  for (int l = 0; l < 16; l++) {
    float pr[8];
#pragma unroll
    for (int j = 0; j < 8; j++) {
      float v = p[(size_t)(j * 16 + l) * E_];
      pr[j] = __fmul_rn(v, v);
    }
    float s01 = __fadd_rn(pr[0], pr[1]);
    float s23 = __fadd_rn(pr[2], pr[3]);
    float s45 = __fadd_rn(pr[4], pr[5]);
    float s67 = __fadd_rn(pr[6], pr[7]);
    lane[l] = __fadd_rn(__fadd_rn(s01, s23), __fadd_rn(s45, s67));
  }
  float bb[8];
#pragma unroll
  for (int l = 0; l < 8; l++) bb[l] = __fadd_rn(lane[l], lane[l + 8]);
  float cc[4];
#pragma unroll
  for (int l = 0; l < 4; l++) cc[l] = __fadd_rn(bb[l], bb[l + 4]);
  part[(size_t)be * 16 + blk] =
      __fadd_rn(__fadd_rn(cc[0], cc[1]), __fadd_rn(cc[2], cc[3]));
}

// K0b: exact final tree over the 16 block values (verified r7).
__global__ __launch_bounds__(256) void k_sqnp_fin(const float* __restrict__ part,
                                                  float* __restrict__ sq) {
  const int t = blockIdx.x * 256 + threadIdx.x;
  if (t >= B_ * E_) return;
  const float* bs = part + (size_t)t * 16;
  float t1[8], t2[4];
#pragma unroll
  for (int l = 0; l < 8; l++) t1[l] = __fadd_rn(bs[2 * l], bs[2 * l + 1]);
#pragma unroll
  for (int l = 0; l < 4; l++) t2[l] = __fadd_rn(t1[2 * l], t1[2 * l + 1]);
  sq[t] = __fadd_rn(__fadd_rn(t2[0], t2[1]), __fadd_rn(t2[2], t2[3]));
}

// ---------------------------------------------------------------------------
// K1: Gram, numpy-exact sequential no-FMA chain, symmetric tiles (verified r7).
// ---------------------------------------------------------------------------
__global__ __launch_bounds__(256) void k_gram_sym(const float* __restrict__ x,
                                                  float* __restrict__ g) {
  __shared__ float xs[32][36];
  __shared__ float ys[32][36];
  int p = blockIdx.x;                    // 0..135 upper-tri pair index
  const int b = blockIdx.y;
  int ti = 0;
  while (p >= 16 - ti) { p -= 16 - ti; ti++; }
  const int tj = ti + p;
  const int i0 = ti * 32, j0 = tj * 32;
  const int tid = threadIdx.x;
  const int li = tid & 15, lj = tid >> 4;
  const int snn = tid >> 3, sc4 = (tid & 7) * 4;
  const float* xb = x + (size_t)b * N_ * E_;

  float a00 = 0.f, a01 = 0.f, a10 = 0.f, a11 = 0.f;
  float4 px = *(const float4*)(xb + (size_t)snn * E_ + i0 + sc4);
  float4 py = *(const float4*)(xb + (size_t)snn * E_ + j0 + sc4);

  for (int n0 = 0; n0 < N_; n0 += 32) {
    __syncthreads();
    *(float4*)&xs[snn][sc4] = px;
    *(float4*)&ys[snn][sc4] = py;
    __syncthreads();
    if (n0 + 32 < N_) {
      px = *(const float4*)(xb + (size_t)(n0 + 32 + snn) * E_ + i0 + sc4);
      py = *(const float4*)(xb + (size_t)(n0 + 32 + snn) * E_ + j0 + sc4);
    }
#pragma unroll
    for (int nn = 0; nn < 32; nn++) {
      const float2 va = *(const float2*)&xs[nn][li * 2];
      const float2 vb = *(const float2*)&ys[nn][lj * 2];
      a00 = __fadd_rn(a00, __fmul_rn(va.x, vb.x));
      a01 = __fadd_rn(a01, __fmul_rn(va.x, vb.y));
      a10 = __fadd_rn(a10, __fmul_rn(va.y, vb.x));
      a11 = __fadd_rn(a11, __fmul_rn(va.y, vb.y));
    }
  }
  float* gb = g + (size_t)b * E_ * E_;
  const int i = i0 + li * 2, j = j0 + lj * 2;
  gb[(size_t)i * E_ + j]           = a00;
  gb[(size_t)i * E_ + j + 1]       = a01;
  gb[(size_t)(i + 1) * E_ + j]     = a10;
  gb[(size_t)(i + 1) * E_ + j + 1] = a11;
  if (ti != tj) {
    gb[(size_t)j * E_ + i]           = a00;
    gb[(size_t)(j + 1) * E_ + i]     = a01;
    gb[(size_t)j * E_ + i + 1]       = a10;
    gb[(size_t)(j + 1) * E_ + i + 1] = a11;
  }
}

// ---------------------------------------------------------------------------
// K2: top-16 smallest dist, fp32 formula, ties -> lower index (verified r4).
// ---------------------------------------------------------------------------
__global__ __launch_bounds__(256) void k_topk(const float* __restrict__ sq,
                                              const float* __restrict__ g,
                                              int* __restrict__ idxout) {
  const int bi = blockIdx.x;            // b*E + i
  const int b = bi >> 9, i = bi & (E_ - 1);
  const int tid = threadIdx.x;
  const float* gb = g + ((size_t)b * E_ + i) * E_;
  const float* sqb = sq + ((size_t)b << 9);
  __shared__ float val[E_];
  __shared__ float rv[256];
  __shared__ int ri[256];
  const float sqi = sqb[i];
  for (int j = tid; j < E_; j += 256) {
    val[j] = __fsub_rn(__fadd_rn(sqi, sqb[j]), __fmul_rn(2.0f, gb[j]));
  }
  __syncthreads();
  for (int t = 0; t < KNN_; t++) {
    float best = 3.0e38f; int bidx = E_;
    for (int j = tid; j < E_; j += 256) {
      float v = val[j];
      if (v < best) { best = v; bidx = j; }
    }
    rv[tid] = best; ri[tid] = bidx;
    __syncthreads();
    for (int s = 128; s > 0; s >>= 1) {
      if (tid < s) {
        float v2 = rv[tid + s]; int i2 = ri[tid + s];
        if (v2 < rv[tid] || (v2 == rv[tid] && i2 < ri[tid])) {
          rv[tid] = v2; ri[tid] = i2;
        }
      }
      __syncthreads();
    }
    if (tid == 0) {
      idxout[(size_t)bi * KNN_ + t] = ri[0];
      val[ri[0]] = 3.0e38f;
    }
    __syncthreads();
  }
}

// ---------------------------------------------------------------------------
// K3: x_knn mean + interleaved q into output's q half (verified r4).
// ---------------------------------------------------------------------------
__global__ __launch_bounds__(256) void k_knnmean(const float* __restrict__ x,
                                                 const int* __restrict__ idx,
                                                 float* __restrict__ out) {
  const int n = blockIdx.x, b = blockIdx.y;
  const int tid = threadIdx.x;
  __shared__ float xrow[E_];
  const float* xr = x + ((size_t)b * N_ + n) * E_;
  for (int i = tid; i < E_; i += 256) xrow[i] = xr[i];
  __syncthreads();
  float* orow = out + ((size_t)b * (2 * N_) + n) * EMB_;
  for (int i = tid; i < E_; i += 256) {
    const int* id = idx + ((size_t)b * E_ + i) * KNN_;
    float s = 0.f;
#pragma unroll
    for (int t = 0; t < KNN_; t++) s = __fadd_rn(s, xrow[id[t]]);
    float2 w; w.x = xrow[i]; w.y = s * (1.0f / 16.0f);
    *(float2*)&orow[2 * i] = w;
  }
}

// ---------------------------------------------------------------------------
// cvt: fp32 -> bf16, 8 elems/thread, contiguous.
// ---------------------------------------------------------------------------
__global__ __launch_bounds__(256) void k_cvt(const float* __restrict__ src,
                                             short* __restrict__ dst, int n8) {
  const int t = blockIdx.x * 256 + threadIdx.x;
  if (t >= n8) return;
  const float* s = src + (size_t)t * 8;
  float4 a = *(const float4*)s, b = *(const float4*)(s + 4);
  short8_t v;
  v[0] = f2bf(a.x); v[1] = f2bf(a.y); v[2] = f2bf(a.z); v[3] = f2bf(a.w);
  v[4] = f2bf(b.x); v[5] = f2bf(b.y); v[6] = f2bf(b.z); v[7] = f2bf(b.w);
  *(short8_t*)(dst + (size_t)t * 8) = v;
}

// cvt of q (strided: rows live in out's q-half with batch stride 2N*EMB)
__global__ __launch_bounds__(256) void k_cvt_q(const float* __restrict__ outq,
                                               short* __restrict__ dst) {
  const int t = blockIdx.x * 256 + threadIdx.x;
  const int row = t >> 7, c = (t & 127) * 8;
  const int b = row >> 11, n = row & (N_ - 1);
  const float* s = outq + ((size_t)b * 2 * N_ + n) * EMB_ + c;
  float4 a = *(const float4*)s, bb = *(const float4*)(s + 4);
  short8_t v;
  v[0] = f2bf(a.x);  v[1] = f2bf(a.y);  v[2] = f2bf(a.z);  v[3] = f2bf(a.w);
  v[4] = f2bf(bb.x); v[5] = f2bf(bb.y); v[6] = f2bf(bb.z); v[7] = f2bf(bb.w);
  *(short8_t*)(dst + (size_t)row * EMB_ + c) = v;
}

// ---------------------------------------------------------------------------
// K4: bf16 MFMA projection GEMM (verified r6/r7).
// ---------------------------------------------------------------------------
template<int MODE>
__global__ __launch_bounds__(256) void k_gemm_bf16(
    const short* __restrict__ X, const short* __restrict__ W,
    const float* __restrict__ bias, short* __restrict__ Yb,
    float* __restrict__ Yf) {
  __shared__ __align__(16) short As[128 * 64];
  __shared__ __align__(16) short Bs[128 * 64];
  const int tid = threadIdx.x;
  const int row0 = blockIdx.x * 128, col0 = blockIdx.y * 128;
  const int l = tid & 63, lg = l >> 4, lq = l & 15;
  const int w = tid >> 6, wm = w >> 1, wn = w & 1;
  float4_t acc[4][4];
#pragma unroll
  for (int i = 0; i < 4; i++)
#pragma unroll
    for (int j = 0; j < 4; j++) {
      acc[i][j][0] = 0.f; acc[i][j][1] = 0.f; acc[i][j][2] = 0.f; acc[i][j][3] = 0.f;
    }

  int rr_[4], cc_[4];
#pragma unroll
  for (int ii = 0; ii < 4; ii++) {
    const int cid = ii * 256 + tid;
    rr_[ii] = cid >> 3; cc_[ii] = cid & 7;
  }
  short8_t ar[4], br[4];
#pragma unroll
  for (int ii = 0; ii < 4; ii++) {
    ar[ii] = *(const short8_t*)(X + (size_t)(row0 + rr_[ii]) * EMB_ + cc_[ii] * 8);
    br[ii] = *(const short8_t*)(W + (size_t)(col0 + rr_[ii]) * EMB_ + cc_[ii] * 8);
  }

  for (int kt = 0; kt < 16; kt++) {
    __syncthreads();
#pragma unroll
    for (int ii = 0; ii < 4; ii++) {
      const int idx = rr_[ii] * 64 + ((cc_[ii] * 8) ^ ((rr_[ii] & 7) << 3));
      *(short8_t*)&As[idx] = ar[ii];
      *(short8_t*)&Bs[idx] = br[ii];
    }
    __syncthreads();
    if (kt < 15) {
#pragma unroll
      for (int ii = 0; ii < 4; ii++) {
        ar[ii] = *(const short8_t*)(X + (size_t)(row0 + rr_[ii]) * EMB_ + (kt + 1) * 64 + cc_[ii] * 8);
        br[ii] = *(const short8_t*)(W + (size_t)(col0 + rr_[ii]) * EMB_ + (kt + 1) * 64 + cc_[ii] * 8);
      }
    }
#pragma unroll
    for (int kk = 0; kk < 2; kk++) {
      short8_t af[4], bf[4];
#pragma unroll
      for (int mi = 0; mi < 4; mi++) {
        const int r = wm * 64 + mi * 16 + lq;
        af[mi] = *(const short8_t*)&As[r * 64 + ((kk * 32 + lg * 8) ^ ((r & 7) << 3))];
      }
#pragma unroll
      for (int ni = 0; ni < 4; ni++) {
        const int r = wn * 64 + ni * 16 + lq;
        bf[ni] = *(const short8_t*)&Bs[r * 64 + ((kk * 32 + lg * 8) ^ ((r & 7) << 3))];
      }
#pragma unroll
      for (int mi = 0; mi < 4; mi++)
#pragma unroll
        for (int ni = 0; ni < 4; ni++)
          acc[mi][ni] = __builtin_amdgcn_mfma_f32_16x16x32_bf16(af[mi], bf[ni], acc[mi][ni], 0, 0, 0);
    }
  }
#pragma unroll
  for (int ni = 0; ni < 4; ni++) {
    const int col = col0 + wn * 64 + ni * 16 + lq;
    const float bv = bias[col];
#pragma unroll
    for (int mi = 0; mi < 4; mi++) {
#pragma unroll
      for (int j = 0; j < 4; j++) {
        const int m = row0 + wm * 64 + mi * 16 + lg * 4 + j;
        const float v = acc[mi][ni][j] + bv;
        if (MODE == 0) {
          Yb[(size_t)m * EMB_ + col] = f2bf(v);
        } else if (MODE == 1) {
          const int b2 = m >> 11, n2 = m & (N_ - 1);
          Yf[((size_t)b2 * 2 * N_ + N_ + n2) * EMB_ + col] = v;
        } else {
          const int b2 = m >> 11, n2 = m & (N_ - 1);
          Yb[((size_t)b2 * EMB_ + col) * N_ + n2] = f2bf(v);
        }
      }
    }
  }
}

// ---------------------------------------------------------------------------
// K5: bf16 flash attention, r10: 32x32x16 MFMA (2x FLOP per LDS b128 read),
// 32 q-rows/wave, 128 q/block, 512 blocks. Swapped QK^T -> q = lane&31 is
// lane-local (C/D: col=lane&31, row=(reg&3)+8*(reg>>2)+4*(lane>>5), m101).
// Keeps r9's defer-max + exp2-fold + packed cvt + T14 staging + setprio.
// ---------------------------------------------------------------------------
__global__ __launch_bounds__(256, 2) void k_flash_bf16(
    const short* __restrict__ Qg, const short* __restrict__ Kg,
    const short* __restrict__ Vtg, short* __restrict__ Og) {
  __shared__ __align__(16) short Ks[64 * 128];    // [key][d] swizzled
  __shared__ __align__(16) short Vs[128 * 64];    // [d][key] swizzled (V^T)
  __shared__ __align__(16) short Ps[4][32 * 64];  // per-wave [q][key] swizzled
  const int tid = threadIdx.x;
  const int w = tid >> 6, l = tid & 63;
  const int hi = l >> 5, l5 = l & 31;
  const int bid = blockIdx.x;
  // 512 blocks = 8 xcd * 4 bh * 16 rt
  const int bh = (bid & 7) * 4 + ((bid >> 3) >> 4);
  const int rt = (bid >> 3) & 15;
  const int b = bh >> 3, h = bh & 7;
  const float c1 = 0.08838834764831845f * 1.4426950408889634f;  // scale*log2e
  const size_t bhoff = (size_t)b * N_ * EMB_ + (size_t)h * D_;
  const int psw = (l5 & 7) << 3;

  // staging geometry (identical to r9)
  int koff[4], vofs[4], klds[4], vlds[4];
#pragma unroll
  for (int ii = 0; ii < 4; ii++) {
    const int cid = ii * 256 + tid;
    const int kr = cid >> 4, kc = cid & 15;
    const int vr = cid >> 3, vc = cid & 7;
    koff[ii] = kr * EMB_ + kc * 8;
    vofs[ii] = vr * N_ + vc * 8;
    klds[ii] = kr * 128 + ((kc * 8) ^ ((kr & 7) << 3));
    vlds[ii] = vr * 64 + ((vc * 8) ^ ((vr & 7) << 3));
  }
  const short* Kt0 = Kg + bhoff;
  const short* Vt0 = Vtg + (size_t)b * EMB_ * N_ + (size_t)(h * D_) * N_;

  // Q fragments (B operand): q = l5 (lane-local), k = s*16 + hi*8 + j
  short8_t qf[8];
  {
    const short* qrow = Qg + bhoff + (size_t)(rt * 128 + w * 32 + l5) * EMB_;
#pragma unroll
    for (int s = 0; s < 8; s++)
      qf[s] = *(const short8_t*)(qrow + s * 16 + hi * 8);
  }
  float16_t oacc[4];
#pragma unroll
  for (int dg = 0; dg < 4; dg++)
#pragma unroll
    for (int r = 0; r < 16; r++) oacc[dg][r] = 0.f;
  float m = -3.0e38f, lsum = 0.f;

  short8_t kreg[4], vreg[4];
#pragma unroll
  for (int ii = 0; ii < 4; ii++) {       // prologue: tile 0 -> regs
    kreg[ii] = *(const short8_t*)(Kt0 + koff[ii]);
    vreg[ii] = *(const short8_t*)(Vt0 + vofs[ii]);
  }
#pragma unroll
  for (int ii = 0; ii < 4; ii++) {       // regs -> LDS
    *(short8_t*)&Ks[klds[ii]] = kreg[ii];
    *(short8_t*)&Vs[vlds[ii]] = vreg[ii];
  }
  __syncthreads();

  for (int kt = 0; kt < N_ / 64; kt++) {
    if (kt + 1 < N_ / 64) {              // issue next tile's loads early (T14)
      const short* Kt = Kt0 + (size_t)((kt + 1) * 64) * EMB_;
      const short* Vt = Vt0 + (kt + 1) * 64;
#pragma unroll
      for (int ii = 0; ii < 4; ii++) {
        kreg[ii] = *(const short8_t*)(Kt + koff[ii]);
        vreg[ii] = *(const short8_t*)(Vt + vofs[ii]);
      }
    }

    // ---- S^T = K . Q^T  (two 32-key groups, 8 k-slices each)
    float16_t s0, s1;
#pragma unroll
    for (int r = 0; r < 16; r++) { s0[r] = 0.f; s1[r] = 0.f; }
    __builtin_amdgcn_s_setprio(1);
#pragma unroll
    for (int s = 0; s < 8; s++) {
      const int col = (s * 16 + hi * 8) ^ psw;
      short8_t kf0 = *(const short8_t*)&Ks[l5 * 128 + col];
      short8_t kf1 = *(const short8_t*)&Ks[(32 + l5) * 128 + col];
      s0 = __builtin_amdgcn_mfma_f32_32x32x16_bf16(kf0, qf[s], s0, 0, 0, 0);
      s1 = __builtin_amdgcn_mfma_f32_32x32x16_bf16(kf1, qf[s], s1, 0, 0, 0);
    }
    __builtin_amdgcn_s_setprio(0);

    // ---- online softmax with defer-max; p = exp2(S*c1 - m*c1)
    float tm = s0[0];
#pragma unroll
    for (int r = 1; r < 16; r++) tm = fmaxf(tm, s0[r]);
#pragma unroll
    for (int r = 0; r < 16; r++) tm = fmaxf(tm, s1[r]);
    tm = fmaxf(tm, __shfl_xor(tm, 32));
    if (__any(tm > m + 62.7f)) {         // 62.7*c1 = 8 -> P <= 2^8
      const float mn = fmaxf(m, tm);
      const float alpha = fexp2((m - mn) * c1);
      m = mn;
      lsum *= alpha;
#pragma unroll
      for (int dg = 0; dg < 4; dg++)
#pragma unroll
        for (int r = 0; r < 16; r++) oacc[dg][r] *= alpha;
    }
    const float mc1 = m * c1;
    float ps = 0.f;
#pragma unroll
    for (int g = 0; g < 4; g++) {        // tile 0: keys 8g+4hi+{0..3}
      float p0 = fexp2(__builtin_fmaf(s0[4 * g + 0], c1, -mc1));
      float p1 = fexp2(__builtin_fmaf(s0[4 * g + 1], c1, -mc1));
      float p2 = fexp2(__builtin_fmaf(s0[4 * g + 2], c1, -mc1));
      float p3 = fexp2(__builtin_fmaf(s0[4 * g + 3], c1, -mc1));
      ps += (p0 + p1) + (p2 + p3);
      uint2 pw; pw.x = pk2bf(p0, p1); pw.y = pk2bf(p2, p3);
      *(uint2*)&Ps[w][l5 * 64 + ((g * 8 + hi * 4) ^ psw)] = pw;
    }
#pragma unroll
    for (int g = 0; g < 4; g++) {        // tile 1: keys 32+8g+4hi+{0..3}
      float p0 = fexp2(__builtin_fmaf(s1[4 * g + 0], c1, -mc1));
      float p1 = fexp2(__builtin_fmaf(s1[4 * g + 1], c1, -mc1));
      float p2 = fexp2(__builtin_fmaf(s1[4 * g + 2], c1, -mc1));
      float p3 = fexp2(__builtin_fmaf(s1[4 * g + 3], c1, -mc1));
      ps += (p0 + p1) + (p2 + p3);
      uint2 pw; pw.x = pk2bf(p0, p1); pw.y = pk2bf(p2, p3);
      *(uint2*)&Ps[w][l5 * 64 + ((32 + g * 8 + hi * 4) ^ psw)] = pw;
    }
    ps += __shfl_xor(ps, 32);
    lsum += ps;

    // ---- O^T += V^T . P^T  (4 d-groups x 4 key-slices)
    __builtin_amdgcn_s_setprio(1);
#pragma unroll
    for (int ks = 0; ks < 4; ks++) {
      const int col = (ks * 16 + hi * 8) ^ psw;
      short8_t pf = *(const short8_t*)&Ps[w][l5 * 64 + col];
#pragma unroll
      for (int dg = 0; dg < 4; dg++) {
        short8_t vf = *(const short8_t*)&Vs[(dg * 32 + l5) * 64 + col];
        oacc[dg] = __builtin_amdgcn_mfma_f32_32x32x16_bf16(vf, pf, oacc[dg], 0, 0, 0);
      }
    }
    __builtin_amdgcn_s_setprio(0);

    __syncthreads();                     // all waves done reading Ks/Vs
    if (kt + 1 < N_ / 64) {
#pragma unroll
      for (int ii = 0; ii < 4; ii++) {   // write-late (waits vmcnt on regs)
        *(short8_t*)&Ks[klds[ii]] = kreg[ii];
        *(short8_t*)&Vs[vlds[ii]] = vreg[ii];
      }
      __syncthreads();                   // writes visible before next QK^T
    }
  }

  // ---- epilogue: O[q][d], d = dg*32 + 8g + 4hi + {0..3}, q = l5 (lane-local)
  const float linv = 1.0f / lsum;
  short* orow = Og + bhoff + (size_t)(rt * 128 + w * 32 + l5) * EMB_;
#pragma unroll
  for (int dg = 0; dg < 4; dg++) {
#pragma unroll
    for (int g = 0; g < 4; g++) {
      float p0 = oacc[dg][4 * g + 0] * linv;
      float p1 = oacc[dg][4 * g + 1] * linv;
      float p2 = oacc[dg][4 * g + 2] * linv;
      float p3 = oacc[dg][4 * g + 3] * linv;
      uint2 ow; ow.x = pk2bf(p0, p1); ow.y = pk2bf(p2, p3);
      *(uint2*)&orow[dg * 32 + g * 8 + hi * 4] = ow;
    }
  }
}

// ---------------------------------------------------------------------------
extern "C" void kernel_launch(void* const* d_in, const int* in_sizes, int n_in,
                              void* d_out, int out_size, void* d_ws, size_t ws_size,
                              hipStream_t stream) {
  const float* x     = (const float*)d_in[0];
  const float* x_enc = (const float*)d_in[1];
  const float* w_in  = (const float*)d_in[2];
  const float* b_in  = (const float*)d_in[3];
  const float* w_out = (const float*)d_in[4];
  const float* b_out = (const float*)d_in[5];
  float* out = (float*)d_out;
  char* wsb = (char*)d_ws;

  const size_t oG    = 0;
  const size_t oSq   = oG + (size_t)B_ * E_ * E_ * 4;
  const size_t oPart = oSq + (size_t)B_ * E_ * 4;
  const size_t oIdx  = oPart + (size_t)B_ * E_ * 16 * 4;
  const size_t oXq   = (oIdx + (size_t)B_ * E_ * KNN_ * 4 + 255) & ~(size_t)255;
  const size_t sB    = (size_t)B_ * N_ * EMB_ * 2;
  const size_t oXe   = oXq + sB;
  const size_t oWin  = oXe + sB;
  const size_t oWo   = oWin + 3ull * EMB_ * EMB_ * 2;
  const size_t oQ    = oWo + (size_t)EMB_ * EMB_ * 2;
  const size_t oK    = oQ + sB;
  const size_t oV    = oK + sB;
  const size_t oO    = oV + sB;
  const size_t need  = oO + sB;

  float* g    = (float*)(wsb + oG);
  float* sqv  = (float*)(wsb + oSq);
  float* part = (float*)(wsb + oPart);
  int*   idx  = (int*)(wsb + oIdx);
  short* Xq   = (short*)(wsb + oXq);
  short* Xe   = (short*)(wsb + oXe);
  short* Win  = (short*)(wsb + oWin);
  short* Wo   = (short*)(wsb + oWo);
  short* Qb   = (short*)(wsb + oQ);
  short* Kb   = (short*)(wsb + oK);
  short* Vb   = (short*)(wsb + oV);
  short* Ob   = (ws_size >= need) ? (short*)(wsb + oO) : Qb;

  // 1) kNN emulating the numpy reference's fp32 numerics exactly
  k_sqnp_part<<<dim3(B_ * E_ * 16 / 256), 256, 0, stream>>>(x, part);
  k_sqnp_fin<<<dim3(B_ * E_ / 256), 256, 0, stream>>>(part, sqv);
  k_gram_sym<<<dim3(136, B_), 256, 0, stream>>>(x, g);
  k_topk<<<dim3(B_ * E_), 256, 0, stream>>>(sqv, g, idx);
  k_knnmean<<<dim3(N_, B_), 256, 0, stream>>>(x, idx, out);

  // 2) bf16 conversions
  k_cvt<<<dim3(4096), 256, 0, stream>>>(x_enc, Xe, B_ * N_ * EMB_ / 8);
  k_cvt<<<dim3(1536), 256, 0, stream>>>(w_in, Win, 3 * EMB_ * EMB_ / 8);
  k_cvt<<<dim3(512), 256, 0, stream>>>(w_out, Wo, EMB_ * EMB_ / 8);
  k_cvt_q<<<dim3(4096), 256, 0, stream>>>(out, Xq);

  // 3) projections (bf16 MFMA); V written transposed for flash
  k_gemm_bf16<0><<<dim3(64, 8), 256, 0, stream>>>(Xq, Win, b_in, Qb, nullptr);
  k_gemm_bf16<0><<<dim3(64, 8), 256, 0, stream>>>(Xe, Win + (size_t)EMB_ * EMB_,
                                                  b_in + EMB_, Kb, nullptr);
  k_gemm_bf16<2><<<dim3(64, 8), 256, 0, stream>>>(Xe, Win + 2ull * EMB_ * EMB_,
                                                  b_in + 2 * EMB_, Vb, nullptr);

  // 4) attention (bf16 MFMA flash, 32x32x16, V^T input)
  k_flash_bf16<<<dim3(512), 256, 0, stream>>>(Qb, Kb, Vb, Ob);

  // 5) output projection -> fp32 into out rows [N, 2N)
  k_gemm_bf16<1><<<dim3(64, 8), 256, 0, stream>>>(Ob, Wo, b_out, nullptr, out);
}

// Round 11
// 343.472 us; speedup vs baseline: 7.7117x; 1.0329x over previous
//
#include <hip/hip_runtime.h>
#include <hip/hip_bf16.h>

#define B_ 4
#define N_ 2048
#define E_ 512
#define EMB_ 1024
#define H_ 8
#define D_ 128
#define KNN_ 16

typedef short short8_t __attribute__((ext_vector_type(8)));
typedef short short4_t __attribute__((ext_vector_type(4)));
typedef float float4_t __attribute__((ext_vector_type(4)));
typedef float float16_t __attribute__((ext_vector_type(16)));

__device__ __forceinline__ short f2bf(float f) {
  unsigned u = __float_as_uint(f);
  unsigned r = u + 0x7fffu + ((u >> 16) & 1u);   // RNE to bf16
  return (short)(r >> 16);
}

__device__ __forceinline__ unsigned pk2bf(float a, float b) {
  float2 f; f.x = a; f.y = b;
  __hip_bfloat162 h = __float22bfloat162_rn(f);
  return *(unsigned*)&h;
}

__device__ __forceinline__ float fexp2(float x) {
  return __builtin_amdgcn_exp2f(x);
}

// async global->LDS, 16 B per lane (per-lane global addr, wave-linear LDS dest)
__device__ __forceinline__ void gload16(const short* g, short* l) {
  __builtin_amdgcn_global_load_lds(
      (const __attribute__((address_space(1))) void*)g,
      (__attribute__((address_space(3))) void*)l, 16, 0, 0);
}

// ---------------------------------------------------------------------------
// K0a: partial pairwise sums for sq = np.sum(xt*xt, -1) (verified r7).
// ---------------------------------------------------------------------------
__global__ __launch_bounds__(256) void k_sqnp_part(const float* __restrict__ x,
                                                   float* __restrict__ part) {
  const int t = blockIdx.x * 256 + threadIdx.x;
  if (t >= B_ * E_ * 16) return;
  const int be = t & (B_ * E_ - 1), blk = t >> 11;
  const int b = be >> 9, e = be & (E_ - 1);
  const float* p = x + (size_t)b * N_ * E_ + (size_t)blk * 128 * E_ + e;
  float lane[16];
#pragma unroll
  for (int l = 0; l < 16; l++) {
    float pr[8];
#pragma unroll
    for (int j = 0; j < 8; j++) {
      float v = p[(size_t)(j * 16 + l) * E_];
      pr[j] = __fmul_rn(v, v);
    }
    float s01 = __fadd_rn(pr[0], pr[1]);
    float s23 = __fadd_rn(pr[2], pr[3]);
    float s45 = __fadd_rn(pr[4], pr[5]);
    float s67 = __fadd_rn(pr[6], pr[7]);
    lane[l] = __fadd_rn(__fadd_rn(s01, s23), __fadd_rn(s45, s67));
  }
  float bb[8];
#pragma unroll
  for (int l = 0; l < 8; l++) bb[l] = __fadd_rn(lane[l], lane[l + 8]);
  float cc[4];
#pragma unroll
  for (int l = 0; l < 4; l++) cc[l] = __fadd_rn(bb[l], bb[l + 4]);
  part[(size_t)be * 16 + blk] =
      __fadd_rn(__fadd_rn(cc[0], cc[1]), __fadd_rn(cc[2], cc[3]));
}

// K0b: exact final tree over the 16 block values (verified r7).
__global__ __launch_bounds__(256) void k_sqnp_fin(const float* __restrict__ part,
                                                  float* __restrict__ sq) {
  const int t = blockIdx.x * 256 + threadIdx.x;
  if (t >= B_ * E_) return;
  const float* bs = part + (size_t)t * 16;
  float t1[8], t2[4];
#pragma unroll
  for (int l = 0; l < 8; l++) t1[l] = __fadd_rn(bs[2 * l], bs[2 * l + 1]);
#pragma unroll
  for (int l = 0; l < 4; l++) t2[l] = __fadd_rn(t1[2 * l], t1[2 * l + 1]);
  sq[t] = __fadd_rn(__fadd_rn(t2[0], t2[1]), __fadd_rn(t2[2], t2[3]));
}

// ---------------------------------------------------------------------------
// K1 r11: Gram, numpy-exact sequential no-FMA chain. 4x4 register blocking
// (LDS bytes/MAC halved twice vs 2x2 -> LDS off critical path), ONE wave per
// 32x32 unit-pair (544 blocks), private double-buffered LDS, ZERO barriers.
// Chain per output: ascending n, single thread, __fadd_rn(__fmul_rn) ✓exact.
// LDS [2][32][68] fl, quad index XOR-swizzled by (nn&7)<<2 (writes/reads <=2-way).
// ---------------------------------------------------------------------------
__global__ __launch_bounds__(64) void k_gram_sym(const float* __restrict__ x,
                                                 float* __restrict__ g) {
  __shared__ __align__(16) float Xs[2][32][68];
  int p = blockIdx.x;                    // 0..135 upper-tri pair index
  const int b = blockIdx.y;
  int ti = 0;
  while (p >= 16 - ti) { p -= 16 - ti; ti++; }
  const int tj = ti + p;
  const int i0 = ti * 32, j0 = tj * 32;
  const int lane = threadIdx.x;
  const int li = lane & 7, lj = lane >> 3;     // compute: i-quad, j-quad
  const int cq = lane & 7, rn = lane >> 3;     // staging: ch-quad, n-row
  const float* xb = x + (size_t)b * N_ * E_;

  float acc[4][4];
#pragma unroll
  for (int u = 0; u < 4; u++)
#pragma unroll
    for (int v = 0; v < 4; v++) acc[u][v] = 0.f;

  float4_t gi[4], gj[4];
#pragma unroll
  for (int ps = 0; ps < 4; ps++) {       // chunk 0 -> regs
    const int n = ps * 8 + rn;
    gi[ps] = *(const float4_t*)(xb + (size_t)n * E_ + i0 + cq * 4);
    gj[ps] = *(const float4_t*)(xb + (size_t)n * E_ + j0 + cq * 4);
  }
#pragma unroll
  for (int ps = 0; ps < 4; ps++) {       // regs -> buf0
    const int nn = ps * 8 + rn;
    const int sw = (nn & 7) << 2;
    *(float4_t*)&Xs[0][nn][(cq * 4) ^ sw] = gi[ps];
    *(float4_t*)&Xs[0][nn][32 + ((cq * 4) ^ sw)] = gj[ps];
  }

  for (int c = 0; c < 64; c++) {
    const int buf = c & 1;
    if (c < 63) {                        // issue next chunk's global loads
      const int nb = (c + 1) * 32;
#pragma unroll
      for (int ps = 0; ps < 4; ps++) {
        const int n = nb + ps * 8 + rn;
        gi[ps] = *(const float4_t*)(xb + (size_t)n * E_ + i0 + cq * 4);
        gj[ps] = *(const float4_t*)(xb + (size_t)n * E_ + j0 + cq * 4);
      }
    }
#pragma unroll
    for (int nn = 0; nn < 32; nn++) {    // compute 32 nn (exact chain order)
      const int sw = (nn & 7) << 2;
      const float4_t va = *(const float4_t*)&Xs[buf][nn][(li * 4) ^ sw];
      const float4_t vb = *(const float4_t*)&Xs[buf][nn][32 + ((lj * 4) ^ sw)];
#pragma unroll
      for (int u = 0; u < 4; u++)
#pragma unroll
        for (int v = 0; v < 4; v++)
          acc[u][v] = __fadd_rn(acc[u][v], __fmul_rn(va[u], vb[v]));
    }
    if (c < 63) {                        // regs -> other buffer (no barrier:
#pragma unroll
      for (int ps = 0; ps < 4; ps++) {   //  single wave, disjoint buffer)
        const int nn = ps * 8 + rn;
        const int sw = (nn & 7) << 2;
        *(float4_t*)&Xs[buf ^ 1][nn][(cq * 4) ^ sw] = gi[ps];
        *(float4_t*)&Xs[buf ^ 1][nn][32 + ((cq * 4) ^ sw)] = gj[ps];
      }
    }
  }
  float* gb = g + (size_t)b * E_ * E_;
#pragma unroll
  for (int u = 0; u < 4; u++) {
#pragma unroll
    for (int v = 0; v < 4; v++) {
      const int i = i0 + li * 4 + u, j = j0 + lj * 4 + v;
      gb[(size_t)i * E_ + j] = acc[u][v];
      if (ti != tj) gb[(size_t)j * E_ + i] = acc[u][v];
    }
  }
}

// ---------------------------------------------------------------------------
// K2: top-16 smallest dist, fp32 formula, ties -> lower index (verified r4).
// ---------------------------------------------------------------------------
__global__ __launch_bounds__(256) void k_topk(const float* __restrict__ sq,
                                              const float* __restrict__ g,
                                              int* __restrict__ idxout) {
  const int bi = blockIdx.x;            // b*E + i
  const int b = bi >> 9, i = bi & (E_ - 1);
  const int tid = threadIdx.x;
  const float* gb = g + ((size_t)b * E_ + i) * E_;
  const float* sqb = sq + ((size_t)b << 9);
  __shared__ float val[E_];
  __shared__ float rv[256];
  __shared__ int ri[256];
  const float sqi = sqb[i];
  for (int j = tid; j < E_; j += 256) {
    val[j] = __fsub_rn(__fadd_rn(sqi, sqb[j]), __fmul_rn(2.0f, gb[j]));
  }
  __syncthreads();
  for (int t = 0; t < KNN_; t++) {
    float best = 3.0e38f; int bidx = E_;
    for (int j = tid; j < E_; j += 256) {
      float v = val[j];
      if (v < best) { best = v; bidx = j; }
    }
    rv[tid] = best; ri[tid] = bidx;
    __syncthreads();
    for (int s = 128; s > 0; s >>= 1) {
      if (tid < s) {
        float v2 = rv[tid + s]; int i2 = ri[tid + s];
        if (v2 < rv[tid] || (v2 == rv[tid] && i2 < ri[tid])) {
          rv[tid] = v2; ri[tid] = i2;
        }
      }
      __syncthreads();
    }
    if (tid == 0) {
      idxout[(size_t)bi * KNN_ + t] = ri[0];
      val[ri[0]] = 3.0e38f;
    }
    __syncthreads();
  }
}

// ---------------------------------------------------------------------------
// K3: x_knn mean + interleaved q into output's q half (verified r4).
// ---------------------------------------------------------------------------
__global__ __launch_bounds__(256) void k_knnmean(const float* __restrict__ x,
                                                 const int* __restrict__ idx,
                                                 float* __restrict__ out) {
  const int n = blockIdx.x, b = blockIdx.y;
  const int tid = threadIdx.x;
  __shared__ float xrow[E_];
  const float* xr = x + ((size_t)b * N_ + n) * E_;
  for (int i = tid; i < E_; i += 256) xrow[i] = xr[i];
  __syncthreads();
  float* orow = out + ((size_t)b * (2 * N_) + n) * EMB_;
  for (int i = tid; i < E_; i += 256) {
    const int* id = idx + ((size_t)b * E_ + i) * KNN_;
    float s = 0.f;
#pragma unroll
    for (int t = 0; t < KNN_; t++) s = __fadd_rn(s, xrow[id[t]]);
    float2 w; w.x = xrow[i]; w.y = s * (1.0f / 16.0f);
    *(float2*)&orow[2 * i] = w;
  }
}

// ---------------------------------------------------------------------------
// cvt: fp32 -> bf16, 8 elems/thread, contiguous.
// ---------------------------------------------------------------------------
__global__ __launch_bounds__(256) void k_cvt(const float* __restrict__ src,
                                             short* __restrict__ dst, int n8) {
  const int t = blockIdx.x * 256 + threadIdx.x;
  if (t >= n8) return;
  const float* s = src + (size_t)t * 8;
  float4 a = *(const float4*)s, b = *(const float4*)(s + 4);
  short8_t v;
  v[0] = f2bf(a.x); v[1] = f2bf(a.y); v[2] = f2bf(a.z); v[3] = f2bf(a.w);
  v[4] = f2bf(b.x); v[5] = f2bf(b.y); v[6] = f2bf(b.z); v[7] = f2bf(b.w);
  *(short8_t*)(dst + (size_t)t * 8) = v;
}

// cvt of q (strided: rows live in out's q-half with batch stride 2N*EMB)
__global__ __launch_bounds__(256) void k_cvt_q(const float* __restrict__ outq,
                                               short* __restrict__ dst) {
  const int t = blockIdx.x * 256 + threadIdx.x;
  const int row = t >> 7, c = (t & 127) * 8;
  const int b = row >> 11, n = row & (N_ - 1);
  const float* s = outq + ((size_t)b * 2 * N_ + n) * EMB_ + c;
  float4 a = *(const float4*)s, bb = *(const float4*)(s + 4);
  short8_t v;
  v[0] = f2bf(a.x);  v[1] = f2bf(a.y);  v[2] = f2bf(a.z);  v[3] = f2bf(a.w);
  v[4] = f2bf(bb.x); v[5] = f2bf(bb.y); v[6] = f2bf(bb.z); v[7] = f2bf(bb.w);
  *(short8_t*)(dst + (size_t)row * EMB_ + c) = v;
}

// ---------------------------------------------------------------------------
// K4 r11: bf16 MFMA projection GEMM with global_load_lds width-16 staging.
// LDS stays LINEAR (gload_lds dest = wave base + lane*16); the XOR swizzle
// moves to the per-lane GLOBAL source addr (rule #21): LDS[r][q^swz]=X[r][q],
// so the fragment read addressing is byte-identical to the verified r6 code.
// ---------------------------------------------------------------------------
template<int MODE>
__global__ __launch_bounds__(256) void k_gemm_bf16(
    const short* __restrict__ X, const short* __restrict__ W,
    const float* __restrict__ bias, short* __restrict__ Yb,
    float* __restrict__ Yf) {
  __shared__ __align__(16) short As[128 * 64];
  __shared__ __align__(16) short Bs[128 * 64];
  const int tid = threadIdx.x;
  const int row0 = blockIdx.x * 128, col0 = blockIdx.y * 128;
  const int l = tid & 63, lg = l >> 4, lq = l & 15;
  const int w = tid >> 6, wm = w >> 1, wn = w & 1;
  float4_t acc[4][4];
#pragma unroll
  for (int i = 0; i < 4; i++)
#pragma unroll
    for (int j = 0; j < 4; j++) {
      acc[i][j][0] = 0.f; acc[i][j][1] = 0.f; acc[i][j][2] = 0.f; acc[i][j][3] = 0.f;
    }

  // pre-swizzled global source offsets + wave-uniform LDS bases
  int soff[4], ldsb[4];
#pragma unroll
  for (int ii = 0; ii < 4; ii++) {
    const int cid = ii * 256 + tid;
    const int r = cid >> 3, c = cid & 7;
    soff[ii] = r * EMB_ + ((c * 8) ^ ((r & 7) << 3));
    ldsb[ii] = (ii * 256 + w * 64) * 8;        // shorts (wave-uniform)
  }
  const short* Xb = X + (size_t)row0 * EMB_;
  const short* Wb = W + (size_t)col0 * EMB_;

  for (int kt = 0; kt < 16; kt++) {
    __syncthreads();                     // all waves done reading LDS
#pragma unroll
    for (int ii = 0; ii < 4; ii++) {
      gload16(Xb + soff[ii] + kt * 64, As + ldsb[ii]);
      gload16(Wb + soff[ii] + kt * 64, Bs + ldsb[ii]);
    }
    __syncthreads();                     // drains vmcnt -> data visible
#pragma unroll
    for (int kk = 0; kk < 2; kk++) {
      short8_t af[4], bf[4];
#pragma unroll
      for (int mi = 0; mi < 4; mi++) {
        const int r = wm * 64 + mi * 16 + lq;
        af[mi] = *(const short8_t*)&As[r * 64 + ((kk * 32 + lg * 8) ^ ((r & 7) << 3))];
      }
#pragma unroll
      for (int ni = 0; ni < 4; ni++) {
        const int r = wn * 64 + ni * 16 + lq;
        bf[ni] = *(const short8_t*)&Bs[r * 64 + ((kk * 32 + lg * 8) ^ ((r & 7) << 3))];
      }
#pragma unroll
      for (int mi = 0; mi < 4; mi++)
#pragma unroll
        for (int ni = 0; ni < 4; ni++)
          acc[mi][ni] = __builtin_amdgcn_mfma_f32_16x16x32_bf16(af[mi], bf[ni], acc[mi][ni], 0, 0, 0);
    }
  }
#pragma unroll
  for (int ni = 0; ni < 4; ni++) {
    const int col = col0 + wn * 64 + ni * 16 + lq;
    const float bv = bias[col];
#pragma unroll
    for (int mi = 0; mi < 4; mi++) {
#pragma unroll
      for (int j = 0; j < 4; j++) {
        const int m = row0 + wm * 64 + mi * 16 + lg * 4 + j;
        const float v = acc[mi][ni][j] + bv;
        if (MODE == 0) {
          Yb[(size_t)m * EMB_ + col] = f2bf(v);
        } else if (MODE == 1) {
          const int b2 = m >> 11, n2 = m & (N_ - 1);
          Yf[((size_t)b2 * 2 * N_ + N_ + n2) * EMB_ + col] = v;
        } else {
          const int b2 = m >> 11, n2 = m & (N_ - 1);
          Yb[((size_t)b2 * EMB_ + col) * N_ + n2] = f2bf(v);
        }
      }
    }
  }
}

// ---------------------------------------------------------------------------
// K5: bf16 flash attention (verified r10): 32x32x16 MFMA, 32 q/wave,
// defer-max + exp2-fold + packed cvt + T14 staging + setprio.
// ---------------------------------------------------------------------------
__global__ __launch_bounds__(256, 2) void k_flash_bf16(
    const short* __restrict__ Qg, const short* __restrict__ Kg,
    const short* __restrict__ Vtg, short* __restrict__ Og) {
  __shared__ __align__(16) short Ks[64 * 128];    // [key][d] swizzled
  __shared__ __align__(16) short Vs[128 * 64];    // [d][key] swizzled (V^T)
  __shared__ __align__(16) short Ps[4][32 * 64];  // per-wave [q][key] swizzled
  const int tid = threadIdx.x;
  const int w = tid >> 6, l = tid & 63;
  const int hi = l >> 5, l5 = l & 31;
  const int bid = blockIdx.x;
  const int bh = (bid & 7) * 4 + ((bid >> 3) >> 4);
  const int rt = (bid >> 3) & 15;
  const int b = bh >> 3, h = bh & 7;
  const float c1 = 0.08838834764831845f * 1.4426950408889634f;  // scale*log2e
  const size_t bhoff = (size_t)b * N_ * EMB_ + (size_t)h * D_;
  const int psw = (l5 & 7) << 3;

  int koff[4], vofs[4], klds[4], vlds[4];
#pragma unroll
  for (int ii = 0; ii < 4; ii++) {
    const int cid = ii * 256 + tid;
    const int kr = cid >> 4, kc = cid & 15;
    const int vr = cid >> 3, vc = cid & 7;
    koff[ii] = kr * EMB_ + kc * 8;
    vofs[ii] = vr * N_ + vc * 8;
    klds[ii] = kr * 128 + ((kc * 8) ^ ((kr & 7) << 3));
    vlds[ii] = vr * 64 + ((vc * 8) ^ ((vr & 7) << 3));
  }
  const short* Kt0 = Kg + bhoff;
  const short* Vt0 = Vtg + (size_t)b * EMB_ * N_ + (size_t)(h * D_) * N_;

  short8_t qf[8];
  {
    const short* qrow = Qg + bhoff + (size_t)(rt * 128 + w * 32 + l5) * EMB_;
#pragma unroll
    for (int s = 0; s < 8; s++)
      qf[s] = *(const short8_t*)(qrow + s * 16 + hi * 8);
  }
  float16_t oacc[4];
#pragma unroll
  for (int dg = 0; dg < 4; dg++)
#pragma unroll
    for (int r = 0; r < 16; r++) oacc[dg][r] = 0.f;
  float m = -3.0e38f, lsum = 0.f;

  short8_t kreg[4], vreg[4];
#pragma unroll
  for (int ii = 0; ii < 4; ii++) {
    kreg[ii] = *(const short8_t*)(Kt0 + koff[ii]);
    vreg[ii] = *(const short8_t*)(Vt0 + vofs[ii]);
  }
#pragma unroll
  for (int ii = 0; ii < 4; ii++) {
    *(short8_t*)&Ks[klds[ii]] = kreg[ii];
    *(short8_t*)&Vs[vlds[ii]] = vreg[ii];
  }
  __syncthreads();

  for (int kt = 0; kt < N_ / 64; kt++) {
    if (kt + 1 < N_ / 64) {
      const short* Kt = Kt0 + (size_t)((kt + 1) * 64) * EMB_;
      const short* Vt = Vt0 + (kt + 1) * 64;
#pragma unroll
      for (int ii = 0; ii < 4; ii++) {
        kreg[ii] = *(const short8_t*)(Kt + koff[ii]);
        vreg[ii] = *(const short8_t*)(Vt + vofs[ii]);
      }
    }

    float16_t s0, s1;
#pragma unroll
    for (int r = 0; r < 16; r++) { s0[r] = 0.f; s1[r] = 0.f; }
    __builtin_amdgcn_s_setprio(1);
#pragma unroll
    for (int s = 0; s < 8; s++) {
      const int col = (s * 16 + hi * 8) ^ psw;
      short8_t kf0 = *(const short8_t*)&Ks[l5 * 128 + col];
      short8_t kf1 = *(const short8_t*)&Ks[(32 + l5) * 128 + col];
      s0 = __builtin_amdgcn_mfma_f32_32x32x16_bf16(kf0, qf[s], s0, 0, 0, 0);
      s1 = __builtin_amdgcn_mfma_f32_32x32x16_bf16(kf1, qf[s], s1, 0, 0, 0);
    }
    __builtin_amdgcn_s_setprio(0);

    float tm = s0[0];
#pragma unroll
    for (int r = 1; r < 16; r++) tm = fmaxf(tm, s0[r]);
#pragma unroll
    for (int r = 0; r < 16; r++) tm = fmaxf(tm, s1[r]);
    tm = fmaxf(tm, __shfl_xor(tm, 32));
    if (__any(tm > m + 62.7f)) {
      const float mn = fmaxf(m, tm);
      const float alpha = fexp2((m - mn) * c1);
      m = mn;
      lsum *= alpha;
#pragma unroll
      for (int dg = 0; dg < 4; dg++)
#pragma unroll
        for (int r = 0; r < 16; r++) oacc[dg][r] *= alpha;
    }
    const float mc1 = m * c1;
    float ps = 0.f;
#pragma unroll
    for (int g = 0; g < 4; g++) {
      float p0 = fexp2(__builtin_fmaf(s0[4 * g + 0], c1, -mc1));
      float p1 = fexp2(__builtin_fmaf(s0[4 * g + 1], c1, -mc1));
      float p2 = fexp2(__builtin_fmaf(s0[4 * g + 2], c1, -mc1));
      float p3 = fexp2(__builtin_fmaf(s0[4 * g + 3], c1, -mc1));
      ps += (p0 + p1) + (p2 + p3);
      uint2 pw; pw.x = pk2bf(p0, p1); pw.y = pk2bf(p2, p3);
      *(uint2*)&Ps[w][l5 * 64 + ((g * 8 + hi * 4) ^ psw)] = pw;
    }
#pragma unroll
    for (int g = 0; g < 4; g++) {
      float p0 = fexp2(__builtin_fmaf(s1[4 * g + 0], c1, -mc1));
      float p1 = fexp2(__builtin_fmaf(s1[4 * g + 1], c1, -mc1));
      float p2 = fexp2(__builtin_fmaf(s1[4 * g + 2], c1, -mc1));
      float p3 = fexp2(__builtin_fmaf(s1[4 * g + 3], c1, -mc1));
      ps += (p0 + p1) + (p2 + p3);
      uint2 pw; pw.x = pk2bf(p0, p1); pw.y = pk2bf(p2, p3);
      *(uint2*)&Ps[w][l5 * 64 + ((32 + g * 8 + hi * 4) ^ psw)] = pw;
    }
    ps += __shfl_xor(ps, 32);
    lsum += ps;

    __builtin_amdgcn_s_setprio(1);
#pragma unroll
    for (int ks = 0; ks < 4; ks++) {
      const int col = (ks * 16 + hi * 8) ^ psw;
      short8_t pf = *(const short8_t*)&Ps[w][l5 * 64 + col];
#pragma unroll
      for (int dg = 0; dg < 4; dg++) {
        short8_t vf = *(const short8_t*)&Vs[(dg * 32 + l5) * 64 + col];
        oacc[dg] = __builtin_amdgcn_mfma_f32_32x32x16_bf16(vf, pf, oacc[dg], 0, 0, 0);
      }
    }
    __builtin_amdgcn_s_setprio(0);

    __syncthreads();
    if (kt + 1 < N_ / 64) {
#pragma unroll
      for (int ii = 0; ii < 4; ii++) {
        *(short8_t*)&Ks[klds[ii]] = kreg[ii];
        *(short8_t*)&Vs[vlds[ii]] = vreg[ii];
      }
      __syncthreads();
    }
  }

  const float linv = 1.0f / lsum;
  short* orow = Og + bhoff + (size_t)(rt * 128 + w * 32 + l5) * EMB_;
#pragma unroll
  for (int dg = 0; dg < 4; dg++) {
#pragma unroll
    for (int g = 0; g < 4; g++) {
      float p0 = oacc[dg][4 * g + 0] * linv;
      float p1 = oacc[dg][4 * g + 1] * linv;
      float p2 = oacc[dg][4 * g + 2] * linv;
      float p3 = oacc[dg][4 * g + 3] * linv;
      uint2 ow; ow.x = pk2bf(p0, p1); ow.y = pk2bf(p2, p3);
      *(uint2*)&orow[dg * 32 + g * 8 + hi * 4] = ow;
    }
  }
}

// ---------------------------------------------------------------------------
extern "C" void kernel_launch(void* const* d_in, const int* in_sizes, int n_in,
                              void* d_out, int out_size, void* d_ws, size_t ws_size,
                              hipStream_t stream) {
  const float* x     = (const float*)d_in[0];
  const float* x_enc = (const float*)d_in[1];
  const float* w_in  = (const float*)d_in[2];
  const float* b_in  = (const float*)d_in[3];
  const float* w_out = (const float*)d_in[4];
  const float* b_out = (const float*)d_in[5];
  float* out = (float*)d_out;
  char* wsb = (char*)d_ws;

  const size_t oG    = 0;
  const size_t oSq   = oG + (size_t)B_ * E_ * E_ * 4;
  const size_t oPart = oSq + (size_t)B_ * E_ * 4;
  const size_t oIdx  = oPart + (size_t)B_ * E_ * 16 * 4;
  const size_t oXq   = (oIdx + (size_t)B_ * E_ * KNN_ * 4 + 255) & ~(size_t)255;
  const size_t sB    = (size_t)B_ * N_ * EMB_ * 2;
  const size_t oXe   = oXq + sB;
  const size_t oWin  = oXe + sB;
  const size_t oWo   = oWin + 3ull * EMB_ * EMB_ * 2;
  const size_t oQ    = oWo + (size_t)EMB_ * EMB_ * 2;
  const size_t oK    = oQ + sB;
  const size_t oV    = oK + sB;
  const size_t oO    = oV + sB;
  const size_t need  = oO + sB;

  float* g    = (float*)(wsb + oG);
  float* sqv  = (float*)(wsb + oSq);
  float* part = (float*)(wsb + oPart);
  int*   idx  = (int*)(wsb + oIdx);
  short* Xq   = (short*)(wsb + oXq);
  short* Xe   = (short*)(wsb + oXe);
  short* Win  = (short*)(wsb + oWin);
  short* Wo   = (short*)(wsb + oWo);
  short* Qb   = (short*)(wsb + oQ);
  short* Kb   = (short*)(wsb + oK);
  short* Vb   = (short*)(wsb + oV);
  short* Ob   = (ws_size >= need) ? (short*)(wsb + oO) : Qb;

  // 1) kNN emulating the numpy reference's fp32 numerics exactly
  k_sqnp_part<<<dim3(B_ * E_ * 16 / 256), 256, 0, stream>>>(x, part);
  k_sqnp_fin<<<dim3(B_ * E_ / 256), 256, 0, stream>>>(part, sqv);
  k_gram_sym<<<dim3(136, B_), 64, 0, stream>>>(x, g);
  k_topk<<<dim3(B_ * E_), 256, 0, stream>>>(sqv, g, idx);
  k_knnmean<<<dim3(N_, B_), 256, 0, stream>>>(x, idx, out);

  // 2) bf16 conversions
  k_cvt<<<dim3(4096), 256, 0, stream>>>(x_enc, Xe, B_ * N_ * EMB_ / 8);
  k_cvt<<<dim3(1536), 256, 0, stream>>>(w_in, Win, 3 * EMB_ * EMB_ / 8);
  k_cvt<<<dim3(512), 256, 0, stream>>>(w_out, Wo, EMB_ * EMB_ / 8);
  k_cvt_q<<<dim3(4096), 256, 0, stream>>>(out, Xq);

  // 3) projections (bf16 MFMA, global_load_lds staging); V written transposed
  k_gemm_bf16<0><<<dim3(64, 8), 256, 0, stream>>>(Xq, Win, b_in, Qb, nullptr);
  k_gemm_bf16<0><<<dim3(64, 8), 256, 0, stream>>>(Xe, Win + (size_t)EMB_ * EMB_,
                                                  b_in + EMB_, Kb, nullptr);
  k_gemm_bf16<2><<<dim3(64, 8), 256, 0, stream>>>(Xe, Win + 2ull * EMB_ * EMB_,
                                                  b_in + 2 * EMB_, Vb, nullptr);

  // 4) attention (bf16 MFMA flash, 32x32x16, V^T input)
  k_flash_bf16<<<dim3(512), 256, 0, stream>>>(Qb, Kb, Vb, Ob);

  // 5) output projection -> fp32 into out rows [N, 2N)
  k_gemm_bf16<1><<<dim3(64, 8), 256, 0, stream>>>(Ob, Wo, b_out, nullptr, out);
}